// Round 1
// baseline (976.671 us; speedup 1.0000x reference)
//
#include <hip/hip_runtime.h>
#include <math.h>

// KME attention, fp32 baseline.
// B=2 S=1024 M=8 D=64 H=8 NF=64
//
// ws layout (floats):
//   qr [B][H][S][128]            @ 0          (2,097,152)
//   kr [B][H][S][128]            @ 2097152    (2,097,152)
//   va [B][H][S][512]            @ 4194304    (8,388,608)   512 = m*64+dd
//   ao [B][S][M][512]            @ 12582912   (8,388,608)   512 = h*64+dd
// total 20,971,520 floats = 80 MiB

#define B_ 2
#define S_ 1024
#define H_ 8

// ---------------------------------------------------------------------------
// Fused projection + RoPE + RFF encode (+ softmax-weighted sum over m).
// One block = (b, h, 8 consecutive s). 256 threads = 4 waves; wave w owns
// sm = w*16 .. w*16+15  (i.e. 2 full s rows x 8 m).
// Phase 1: lane = dd, qa[sm][dd] = atoms[sm] . W_h[dd,:], then RoPE.
// Phase 2: lane = f,  pr[sm][f]  = qa[sm] . freq_h[:,f], then sincos+reduce.
// ---------------------------------------------------------------------------
__global__ __launch_bounds__(256) void k_proj_rff(
    const float* __restrict__ atoms, const float* __restrict__ logw,
    const float* __restrict__ W, const float* __restrict__ freqb,
    const float* __restrict__ logbw, const float* __restrict__ cosT,
    const float* __restrict__ sinT, float* __restrict__ out_rff)
{
  const int s0 = blockIdx.x * 8;
  const int h  = blockIdx.y;
  const int b  = blockIdx.z;
  const int tid = threadIdx.x;
  const int w = tid >> 6, lane = tid & 63;

  __shared__ __align__(16) float Wt[64 * 65];   // Wt[d*65+dd] = W[h*64+dd][d]
  __shared__ __align__(16) float Fq[64 * 64];   // Fq[d*64+f]  = freq[h][d][f]
  __shared__ __align__(16) float As[8 * 8 * 64];// As[sm*64+d]
  __shared__ __align__(16) float Qa[64 * 64];   // Qa[sm*64+dd] roped
  __shared__ __align__(16) float Cs[8 * 64];
  __shared__ __align__(16) float Sn[8 * 64];
  __shared__ float Wm[8 * 8];                   // softmax weights [sl][m]

  const float fscale = __expf(-logbw[h]);
  for (int i = tid; i < 4096; i += 256) {
    const int dd = i >> 6, d = i & 63;
    Wt[d * 65 + dd] = W[h * 4096 + i];          // coalesced read, padded store
    Fq[i] = freqb[h * 4096 + i] * fscale;
  }
  for (int i = tid; i < 4096; i += 256)
    As[i] = atoms[(size_t)(b * S_ + s0) * 512 + i];
  for (int i = tid; i < 512; i += 256) {
    const int sl = i >> 6, d = i & 63;
    Cs[i] = cosT[(s0 + sl) * 64 + d];
    Sn[i] = sinT[(s0 + sl) * 64 + d];
  }
  if (tid < 8) {
    const float* lw = logw + (size_t)(b * S_ + s0 + tid) * 8;
    float mx = lw[0];
    for (int m = 1; m < 8; ++m) mx = fmaxf(mx, lw[m]);
    float e[8], sum = 0.f;
    for (int m = 0; m < 8; ++m) { e[m] = __expf(lw[m] - mx); sum += e[m]; }
    const float inv = 1.0f / sum;
    for (int m = 0; m < 8; ++m) Wm[tid * 8 + m] = e[m] * inv;
  }
  __syncthreads();

  // ---- phase 1: projection, lane = dd ----
  float acc[16];
#pragma unroll
  for (int i = 0; i < 16; ++i) acc[i] = 0.f;
#pragma unroll
  for (int d4 = 0; d4 < 16; ++d4) {
    const float w0 = Wt[(4 * d4 + 0) * 65 + lane];
    const float w1 = Wt[(4 * d4 + 1) * 65 + lane];
    const float w2 = Wt[(4 * d4 + 2) * 65 + lane];
    const float w3 = Wt[(4 * d4 + 3) * 65 + lane];
#pragma unroll
    for (int smi = 0; smi < 16; ++smi) {
      const float4 a = *(const float4*)&As[(w * 16 + smi) * 64 + 4 * d4];
      acc[smi] = fmaf(a.x, w0, fmaf(a.y, w1, fmaf(a.z, w2, fmaf(a.w, w3, acc[smi]))));
    }
  }
  // RoPE: dd<32: a*cos - a[dd+32]*sin ; dd>=32: a*cos + a[dd-32]*sin
#pragma unroll
  for (int smi = 0; smi < 16; ++smi) {
    const int sm = w * 16 + smi, sl = sm >> 3;
    const float other = __shfl_xor(acc[smi], 32);
    const float rot = (lane < 32) ? -other : other;
    Qa[sm * 64 + lane] = acc[smi] * Cs[sl * 64 + lane] + rot * Sn[sl * 64 + lane];
  }
  // phase 2 reads only this wave's Qa rows -> no barrier needed.

  // ---- phase 2: RFF, lane = f ----
  float pr[16];
#pragma unroll
  for (int i = 0; i < 16; ++i) pr[i] = 0.f;
#pragma unroll
  for (int d4 = 0; d4 < 16; ++d4) {
    const float f0 = Fq[(4 * d4 + 0) * 64 + lane];
    const float f1 = Fq[(4 * d4 + 1) * 64 + lane];
    const float f2 = Fq[(4 * d4 + 2) * 64 + lane];
    const float f3 = Fq[(4 * d4 + 3) * 64 + lane];
#pragma unroll
    for (int smi = 0; smi < 16; ++smi) {
      const float4 a = *(const float4*)&Qa[(w * 16 + smi) * 64 + 4 * d4];
      pr[smi] = fmaf(a.x, f0, fmaf(a.y, f1, fmaf(a.z, f2, fmaf(a.w, f3, pr[smi]))));
    }
  }
  float oc0 = 0.f, os0 = 0.f, oc1 = 0.f, os1 = 0.f;
#pragma unroll
  for (int smi = 0; smi < 16; ++smi) {
    const int sm = w * 16 + smi, sl = sm >> 3, m = sm & 7;
    float sv, cv;
    __sincosf(pr[smi], &sv, &cv);
    const float wt = Wm[sl * 8 + m];
    if (smi < 8) { oc0 = fmaf(wt, cv, oc0); os0 = fmaf(wt, sv, os0); }
    else         { oc1 = fmaf(wt, cv, oc1); os1 = fmaf(wt, sv, os1); }
  }
  {
    const int sA = s0 + w * 2;
    float* oA = out_rff + (size_t)((b * H_ + h) * S_ + sA) * 128;
    oA[lane]       = oc0 * 0.125f;   // rff_scale = 1/sqrt(64)
    oA[64 + lane]  = os0 * 0.125f;
    oA[128 + lane] = oc1 * 0.125f;   // next s row (sA+1)
    oA[192 + lane] = os1 * 0.125f;
  }
}

// ---------------------------------------------------------------------------
// V projection (no rope, no rff): va[b,h,s,m*64+dd]
// ---------------------------------------------------------------------------
__global__ __launch_bounds__(256) void k_proj_v(
    const float* __restrict__ atoms, const float* __restrict__ W,
    float* __restrict__ va)
{
  const int s0 = blockIdx.x * 8;
  const int h  = blockIdx.y;
  const int b  = blockIdx.z;
  const int tid = threadIdx.x;
  const int w = tid >> 6, lane = tid & 63;

  __shared__ __align__(16) float Wt[64 * 65];
  __shared__ __align__(16) float As[8 * 8 * 64];

  for (int i = tid; i < 4096; i += 256) {
    const int dd = i >> 6, d = i & 63;
    Wt[d * 65 + dd] = W[h * 4096 + i];
  }
  for (int i = tid; i < 4096; i += 256)
    As[i] = atoms[(size_t)(b * S_ + s0) * 512 + i];
  __syncthreads();

  float acc[16];
#pragma unroll
  for (int i = 0; i < 16; ++i) acc[i] = 0.f;
#pragma unroll
  for (int d4 = 0; d4 < 16; ++d4) {
    const float w0 = Wt[(4 * d4 + 0) * 65 + lane];
    const float w1 = Wt[(4 * d4 + 1) * 65 + lane];
    const float w2 = Wt[(4 * d4 + 2) * 65 + lane];
    const float w3 = Wt[(4 * d4 + 3) * 65 + lane];
#pragma unroll
    for (int smi = 0; smi < 16; ++smi) {
      const float4 a = *(const float4*)&As[(w * 16 + smi) * 64 + 4 * d4];
      acc[smi] = fmaf(a.x, w0, fmaf(a.y, w1, fmaf(a.z, w2, fmaf(a.w, w3, acc[smi]))));
    }
  }
#pragma unroll
  for (int smi = 0; smi < 16; ++smi) {
    const int sm = w * 16 + smi, sl = sm >> 3, m = sm & 7;
    va[(size_t)((b * H_ + h) * S_ + s0 + sl) * 512 + m * 64 + lane] = acc[smi];
  }
}

// ---------------------------------------------------------------------------
// Flash attention, fp32. One block = (b,h, 32 q rows). 256 threads.
// thread t: q = t>>3 (0..31), ko = t&7. Scores for k = ko, ko+8 per chunk
// (KC=16); PV accum owns columns c = ko*64 .. ko*64+63 (i.e. m=ko, all dd).
// Vs is LDS-swizzled (+4*(c>>6)) so the 8 ko-lanes hit 8 distinct bank groups.
// Output written re-organized as ao[b,s,m, h*64+dd] for the Wo GEMM.
// ---------------------------------------------------------------------------
__global__ __launch_bounds__(256) void k_flash(
    const float* __restrict__ qr, const float* __restrict__ kr,
    const float* __restrict__ va, float* __restrict__ ao)
{
  const int qt = blockIdx.x, h = blockIdx.y, b = blockIdx.z;
  const int bh = b * H_ + h;
  const int tid = threadIdx.x;
  const int q = tid >> 3, ko = tid & 7;

  const float* Qg = qr + (size_t)(bh * S_ + qt * 32) * 128;
  const float* Kg = kr + (size_t)bh * S_ * 128;
  const float* Vg = va + (size_t)bh * S_ * 512;

  __shared__ __align__(16) float Qs[32 * 132];
  __shared__ __align__(16) float Ks[16 * 132];
  __shared__ __align__(16) float Vs[16 * 544];
  __shared__ float Ps[32 * 20];

#pragma unroll
  for (int j = 0; j < 4; ++j) {
    const int i = tid + 256 * j;
    const int r = i >> 5, fc = (i & 31) * 4;
    *(float4*)&Qs[r * 132 + fc] = *(const float4*)&Qg[r * 128 + fc];
  }
  float o[64];
#pragma unroll
  for (int i = 0; i < 64; ++i) o[i] = 0.f;
  float m_run = -1e30f, l_run = 0.f;

  for (int ch = 0; ch < 64; ++ch) {
    const int k0 = ch * 16;
#pragma unroll
    for (int j = 0; j < 2; ++j) {
      const int i = tid + 256 * j;
      const int r = i >> 5, fc = (i & 31) * 4;
      *(float4*)&Ks[r * 132 + fc] = *(const float4*)&Kg[(k0 + r) * 128 + fc];
    }
#pragma unroll
    for (int j = 0; j < 8; ++j) {
      const int i = tid + 256 * j;
      const int r = i >> 7, c4 = i & 127;
      *(float4*)&Vs[r * 544 + 4 * c4 + 4 * (c4 >> 4)] =
          *(const float4*)&Vg[(size_t)(k0 + r) * 512 + 4 * c4];
    }
    __syncthreads();

    // scores: 2 k per thread, dot over 128 f
    float sA = 0.f, sB = 0.f;
#pragma unroll 8
    for (int f4 = 0; f4 < 32; ++f4) {
      const float4 qv = *(const float4*)&Qs[q * 132 + 4 * f4];
      const float4 ka = *(const float4*)&Ks[ko * 132 + 4 * f4];
      const float4 kb = *(const float4*)&Ks[(ko + 8) * 132 + 4 * f4];
      sA = fmaf(qv.x, ka.x, fmaf(qv.y, ka.y, fmaf(qv.z, ka.z, fmaf(qv.w, ka.w, sA))));
      sB = fmaf(qv.x, kb.x, fmaf(qv.y, kb.y, fmaf(qv.z, kb.z, fmaf(qv.w, kb.w, sB))));
    }
    // online softmax across the 8-lane q-group (lanes differ in bits 0..2)
    float mx = fmaxf(sA, sB);
    mx = fmaxf(mx, __shfl_xor(mx, 1));
    mx = fmaxf(mx, __shfl_xor(mx, 2));
    mx = fmaxf(mx, __shfl_xor(mx, 4));
    const float mnew = fmaxf(m_run, mx);
    const float p0 = __expf(sA - mnew);
    const float p1 = __expf(sB - mnew);
    float rs = p0 + p1;
    rs += __shfl_xor(rs, 1);
    rs += __shfl_xor(rs, 2);
    rs += __shfl_xor(rs, 4);
    const float scale = __expf(m_run - mnew);
    l_run = l_run * scale + rs;
    m_run = mnew;
    Ps[q * 20 + ko] = p0;       // wave-local (same 8 lanes read back) -> no barrier
    Ps[q * 20 + 8 + ko] = p1;
#pragma unroll
    for (int i = 0; i < 64; ++i) o[i] *= scale;

    const int vb = 68 * ko;
#pragma unroll 4
    for (int k = 0; k < 16; ++k) {
      const float pk = Ps[q * 20 + k];
      const float* vrow = &Vs[k * 544 + vb];
#pragma unroll
      for (int c4 = 0; c4 < 16; ++c4) {
        const float4 v = *(const float4*)&vrow[4 * c4];
        o[4 * c4 + 0] = fmaf(pk, v.x, o[4 * c4 + 0]);
        o[4 * c4 + 1] = fmaf(pk, v.y, o[4 * c4 + 1]);
        o[4 * c4 + 2] = fmaf(pk, v.z, o[4 * c4 + 2]);
        o[4 * c4 + 3] = fmaf(pk, v.w, o[4 * c4 + 3]);
      }
    }
    __syncthreads();
  }

  const float inv = 1.0f / l_run;
  float* ob = ao + (size_t)((b * S_ + qt * 32 + q) * 8 + ko) * 512 + h * 64;
#pragma unroll
  for (int c4 = 0; c4 < 16; ++c4) {
    float4 vv;
    vv.x = o[4 * c4 + 0] * inv; vv.y = o[4 * c4 + 1] * inv;
    vv.z = o[4 * c4 + 2] * inv; vv.w = o[4 * c4 + 3] * inv;
    *(float4*)&ob[4 * c4] = vv;
  }
}

// ---------------------------------------------------------------------------
// out_atoms = ao @ Wo^T  (rows = b,s,m; K=512; N=64), fused log-weight delta.
// One block = (b, 2 s rows => 16 (s,m) rows). lane = d. Wave w owns 4 rows.
// ---------------------------------------------------------------------------
__global__ __launch_bounds__(256) void k_out(
    const float* __restrict__ ao, const float* __restrict__ Wo,
    const float* __restrict__ Ww, const float* __restrict__ qlw,
    float* __restrict__ out)
{
  const int s2 = blockIdx.x;          // 0..511
  const int b = blockIdx.z;
  const int s0 = s2 * 2;
  const int tid = threadIdx.x, w = tid >> 6, lane = tid & 63;

  __shared__ __align__(16) float As[16 * 512];
  __shared__ __align__(16) float WoS[64 * 65];  // WoS[fi*65+d] = Wo[d][ft*64+fi]
  __shared__ float Os[16 * 64];

  const float* abase = ao + (size_t)((b * S_ + s0) * 8) * 512;
#pragma unroll
  for (int j = 0; j < 8; ++j) {
    const int i = tid + 256 * j;
    *(float4*)&As[4 * i] = *(const float4*)&abase[4 * i];
  }
  float acc[4] = {0.f, 0.f, 0.f, 0.f};
  for (int ft = 0; ft < 8; ++ft) {
    __syncthreads();   // covers As staging (ft=0) and WoS reuse (ft>0)
    for (int i = tid; i < 4096; i += 256) {
      const int dwo = i >> 6, fi = i & 63;
      WoS[fi * 65 + dwo] = Wo[dwo * 512 + ft * 64 + fi];
    }
    __syncthreads();
#pragma unroll 8
    for (int fi = 0; fi < 64; ++fi) {
      const float wv = WoS[fi * 65 + lane];
      const int f = ft * 64 + fi;
#pragma unroll
      for (int ri = 0; ri < 4; ++ri)
        acc[ri] = fmaf(As[(w * 4 + ri) * 512 + f], wv, acc[ri]);
    }
  }
#pragma unroll
  for (int ri = 0; ri < 4; ++ri) {
    const int row = w * 4 + ri;                     // sl*8+m
    const int R = (b * S_ + s0) * 8 + row;
    out[(size_t)R * 64 + lane] = acc[ri];
    Os[row * 64 + lane] = acc[ri];
  }
  __syncthreads();
  if (w < 2) {   // wave 0 -> s0, wave 1 -> s0+1
    float mean = 0.f;
#pragma unroll
    for (int m = 0; m < 8; ++m) mean += Os[(w * 8 + m) * 64 + lane];
    mean *= 0.125f;
    float dsel = 0.f;
#pragma unroll
    for (int mw = 0; mw < 8; ++mw) {
      float part = mean * Ww[mw * 64 + lane];
      part += __shfl_xor(part, 1);
      part += __shfl_xor(part, 2);
      part += __shfl_xor(part, 4);
      part += __shfl_xor(part, 8);
      part += __shfl_xor(part, 16);
      part += __shfl_xor(part, 32);
      if (lane == mw) dsel = part;
    }
    if (lane < 8) {
      const int idx = (b * S_ + s0 + w) * 8 + lane;
      out[1048576 + idx] = qlw[idx] + dsel;
    }
  }
}

// ---------------------------------------------------------------------------
extern "C" void kernel_launch(void* const* d_in, const int* in_sizes, int n_in,
                              void* d_out, int out_size, void* d_ws, size_t ws_size,
                              hipStream_t stream)
{
  const float* q_atoms = (const float*)d_in[0];
  const float* q_logw  = (const float*)d_in[1];
  const float* k_atoms = (const float*)d_in[2];
  const float* k_logw  = (const float*)d_in[3];
  const float* v_atoms = (const float*)d_in[4];
  // d_in[5] = v_log_weights (unused by the reference)
  const float* cosT  = (const float*)d_in[6];
  const float* sinT  = (const float*)d_in[7];
  const float* Wq    = (const float*)d_in[8];
  const float* Wk    = (const float*)d_in[9];
  const float* Wv    = (const float*)d_in[10];
  const float* Wo    = (const float*)d_in[11];
  const float* Ww    = (const float*)d_in[12];
  const float* logbw = (const float*)d_in[13];
  const float* rffb  = (const float*)d_in[14];
  float* out = (float*)d_out;

  float* wsf = (float*)d_ws;          // needs 80 MiB of ws
  float* qr = wsf;
  float* kr = wsf + 2097152;
  float* va = wsf + 4194304;
  float* ao = wsf + 12582912;

  const dim3 blk(256);
  k_proj_rff<<<dim3(128, 8, 2), blk, 0, stream>>>(q_atoms, q_logw, Wq, rffb, logbw, cosT, sinT, qr);
  k_proj_rff<<<dim3(128, 8, 2), blk, 0, stream>>>(k_atoms, k_logw, Wk, rffb, logbw, cosT, sinT, kr);
  k_proj_v <<<dim3(128, 8, 2), blk, 0, stream>>>(v_atoms, Wv, va);
  k_flash  <<<dim3(32, 8, 2),  blk, 0, stream>>>(qr, kr, va, ao);
  k_out    <<<dim3(512, 1, 2), blk, 0, stream>>>(ao, Wo, Ww, q_logw, out);
}

// Round 2
// 329.745 us; speedup vs baseline: 2.9619x; 2.9619x over previous
//
#include <hip/hip_runtime.h>
#include <math.h>

// KME attention. B=2 S=1024 M=8 D=64 H=8 NF=64
// Round 2: k_flash rewritten with split-bf16 (hi+lo) MFMA (32x32x16),
// swapped-QK online softmax, in-register P repack, pre-split/transposed/
// swizzled V staged via global_load_lds.
//
// ws layout (bytes), 80 MiB total:
//   qrh  @ 0MB   4MB  ushort [bh][s][128]          (natural)
//   qrl  @ 4MB   4MB
//   krh  @ 8MB   4MB  swizzled-chunk layout [bh][ch=32][8192B]
//   krl  @12MB   4MB
//   va   @16MB  32MB  f32 [bh][s][512]  (REUSED as ao [b][s][m][512] by k_flash)
//   vthi @48MB  16MB  swizzled-chunk [bh][ch=32][32768B]
//   vtlo @64MB  16MB

#define B_ 2
#define S_ 1024
#define H_ 8

typedef __attribute__((ext_vector_type(8))) short short8;
typedef __attribute__((ext_vector_type(16))) float f32x16;
union U4B8 { uint4 u; short8 v; };

__device__ inline unsigned cvt_pk_bf16(float a, float b) {
  unsigned r;
  asm("v_cvt_pk_bf16_f32 %0, %1, %2" : "=v"(r) : "v"(a), "v"(b));
  return r;
}
__device__ inline void bsplit(float v, unsigned short &h, unsigned short &l) {
  unsigned hw = cvt_pk_bf16(v, 0.f);
  float hf = __uint_as_float(hw << 16);
  unsigned lw = cvt_pk_bf16(v - hf, 0.f);
  h = (unsigned short)hw; l = (unsigned short)lw;
}

// ---------------------------------------------------------------------------
// Fused projection + RoPE + RFF encode (+ softmax-weighted sum over m).
// Writes bf16 hi/lo planes. kswz=0: natural [bh][s][128].
// kswz=1: swizzled-chunk layout for k_flash's linear global_load_lds staging.
// ---------------------------------------------------------------------------
__global__ __launch_bounds__(256) void k_proj_rff(
    const float* __restrict__ atoms, const float* __restrict__ logw,
    const float* __restrict__ W, const float* __restrict__ freqb,
    const float* __restrict__ logbw, const float* __restrict__ cosT,
    const float* __restrict__ sinT, char* __restrict__ oh,
    char* __restrict__ ol, int kswz)
{
  const int s0 = blockIdx.x * 8;
  const int h  = blockIdx.y;
  const int b  = blockIdx.z;
  const int tid = threadIdx.x;
  const int w = tid >> 6, lane = tid & 63;

  __shared__ __align__(16) float Wt[64 * 65];
  __shared__ __align__(16) float Fq[64 * 64];
  __shared__ __align__(16) float As[8 * 8 * 64];
  __shared__ __align__(16) float Qa[64 * 64];
  __shared__ __align__(16) float Cs[8 * 64];
  __shared__ __align__(16) float Sn[8 * 64];
  __shared__ float Wm[8 * 8];

  const float fscale = __expf(-logbw[h]);
  for (int i = tid; i < 4096; i += 256) {
    const int dd = i >> 6, d = i & 63;
    Wt[d * 65 + dd] = W[h * 4096 + i];
    Fq[i] = freqb[h * 4096 + i] * fscale;
  }
  for (int i = tid; i < 4096; i += 256)
    As[i] = atoms[(size_t)(b * S_ + s0) * 512 + i];
  for (int i = tid; i < 512; i += 256) {
    const int sl = i >> 6, d = i & 63;
    Cs[i] = cosT[(s0 + sl) * 64 + d];
    Sn[i] = sinT[(s0 + sl) * 64 + d];
  }
  if (tid < 8) {
    const float* lw = logw + (size_t)(b * S_ + s0 + tid) * 8;
    float mx = lw[0];
    for (int m = 1; m < 8; ++m) mx = fmaxf(mx, lw[m]);
    float e[8], sum = 0.f;
    for (int m = 0; m < 8; ++m) { e[m] = __expf(lw[m] - mx); sum += e[m]; }
    const float inv = 1.0f / sum;
    for (int m = 0; m < 8; ++m) Wm[tid * 8 + m] = e[m] * inv;
  }
  __syncthreads();

  float acc[16];
#pragma unroll
  for (int i = 0; i < 16; ++i) acc[i] = 0.f;
#pragma unroll
  for (int d4 = 0; d4 < 16; ++d4) {
    const float w0 = Wt[(4 * d4 + 0) * 65 + lane];
    const float w1 = Wt[(4 * d4 + 1) * 65 + lane];
    const float w2 = Wt[(4 * d4 + 2) * 65 + lane];
    const float w3 = Wt[(4 * d4 + 3) * 65 + lane];
#pragma unroll
    for (int smi = 0; smi < 16; ++smi) {
      const float4 a = *(const float4*)&As[(w * 16 + smi) * 64 + 4 * d4];
      acc[smi] = fmaf(a.x, w0, fmaf(a.y, w1, fmaf(a.z, w2, fmaf(a.w, w3, acc[smi]))));
    }
  }
#pragma unroll
  for (int smi = 0; smi < 16; ++smi) {
    const int sm = w * 16 + smi, sl = sm >> 3;
    const float other = __shfl_xor(acc[smi], 32);
    const float rot = (lane < 32) ? -other : other;
    Qa[sm * 64 + lane] = acc[smi] * Cs[sl * 64 + lane] + rot * Sn[sl * 64 + lane];
  }

  float pr[16];
#pragma unroll
  for (int i = 0; i < 16; ++i) pr[i] = 0.f;
#pragma unroll
  for (int d4 = 0; d4 < 16; ++d4) {
    const float f0 = Fq[(4 * d4 + 0) * 64 + lane];
    const float f1 = Fq[(4 * d4 + 1) * 64 + lane];
    const float f2 = Fq[(4 * d4 + 2) * 64 + lane];
    const float f3 = Fq[(4 * d4 + 3) * 64 + lane];
#pragma unroll
    for (int smi = 0; smi < 16; ++smi) {
      const float4 a = *(const float4*)&Qa[(w * 16 + smi) * 64 + 4 * d4];
      pr[smi] = fmaf(a.x, f0, fmaf(a.y, f1, fmaf(a.z, f2, fmaf(a.w, f3, pr[smi]))));
    }
  }
  float oc0 = 0.f, os0 = 0.f, oc1 = 0.f, os1 = 0.f;
#pragma unroll
  for (int smi = 0; smi < 16; ++smi) {
    const int sm = w * 16 + smi, sl = sm >> 3, m = sm & 7;
    float sv, cv;
    __sincosf(pr[smi], &sv, &cv);
    const float wt = Wm[sl * 8 + m];
    if (smi < 8) { oc0 = fmaf(wt, cv, oc0); os0 = fmaf(wt, sv, os0); }
    else         { oc1 = fmaf(wt, cv, oc1); os1 = fmaf(wt, sv, os1); }
  }
  const int sA = s0 + w * 2;
  const int bh = b * H_ + h;
  if (!kswz) {
    size_t e0 = ((size_t)bh * S_ + sA) * 128 + lane;
    unsigned short hh, ll;
    bsplit(oc0 * 0.125f, hh, ll); ((unsigned short*)oh)[e0] = hh;       ((unsigned short*)ol)[e0] = ll;
    bsplit(os0 * 0.125f, hh, ll); ((unsigned short*)oh)[e0 + 64] = hh;  ((unsigned short*)ol)[e0 + 64] = ll;
    bsplit(oc1 * 0.125f, hh, ll); ((unsigned short*)oh)[e0 + 128] = hh; ((unsigned short*)ol)[e0 + 128] = ll;
    bsplit(os1 * 0.125f, hh, ll); ((unsigned short*)oh)[e0 + 192] = hh; ((unsigned short*)ol)[e0 + 192] = ll;
  } else {
    auto put = [&](int s, int f, float v) {
      const int ch = s >> 5, klr = s & 31;
      const unsigned inner = (unsigned)(((klr << 8) + (f << 1)) ^ ((klr & 7) << 4));
      const size_t off = (size_t)bh * 262144 + (size_t)ch * 8192 + inner;
      unsigned short hh, ll; bsplit(v, hh, ll);
      *(unsigned short*)(oh + off) = hh;
      *(unsigned short*)(ol + off) = ll;
    };
    put(sA,     lane,      oc0 * 0.125f);
    put(sA,     64 + lane, os0 * 0.125f);
    put(sA + 1, lane,      oc1 * 0.125f);
    put(sA + 1, 64 + lane, os1 * 0.125f);
  }
}

// ---------------------------------------------------------------------------
// V projection (unchanged): va[bh][s][m*64+dd] fp32
// ---------------------------------------------------------------------------
__global__ __launch_bounds__(256) void k_proj_v(
    const float* __restrict__ atoms, const float* __restrict__ W,
    float* __restrict__ va)
{
  const int s0 = blockIdx.x * 8;
  const int h  = blockIdx.y;
  const int b  = blockIdx.z;
  const int tid = threadIdx.x;
  const int w = tid >> 6, lane = tid & 63;

  __shared__ __align__(16) float Wt[64 * 65];
  __shared__ __align__(16) float As[8 * 8 * 64];

  for (int i = tid; i < 4096; i += 256) {
    const int dd = i >> 6, d = i & 63;
    Wt[d * 65 + dd] = W[h * 4096 + i];
  }
  for (int i = tid; i < 4096; i += 256)
    As[i] = atoms[(size_t)(b * S_ + s0) * 512 + i];
  __syncthreads();

  float acc[16];
#pragma unroll
  for (int i = 0; i < 16; ++i) acc[i] = 0.f;
#pragma unroll
  for (int d4 = 0; d4 < 16; ++d4) {
    const float w0 = Wt[(4 * d4 + 0) * 65 + lane];
    const float w1 = Wt[(4 * d4 + 1) * 65 + lane];
    const float w2 = Wt[(4 * d4 + 2) * 65 + lane];
    const float w3 = Wt[(4 * d4 + 3) * 65 + lane];
#pragma unroll
    for (int smi = 0; smi < 16; ++smi) {
      const float4 a = *(const float4*)&As[(w * 16 + smi) * 64 + 4 * d4];
      acc[smi] = fmaf(a.x, w0, fmaf(a.y, w1, fmaf(a.z, w2, fmaf(a.w, w3, acc[smi]))));
    }
  }
#pragma unroll
  for (int smi = 0; smi < 16; ++smi) {
    const int sm = w * 16 + smi, sl = sm >> 3, m = sm & 7;
    va[(size_t)((b * H_ + h) * S_ + s0 + sl) * 512 + m * 64 + lane] = acc[smi];
  }
}

// ---------------------------------------------------------------------------
// va f32 [bh][s][c] -> vthi/vtlo bf16 pre-transposed, pre-swizzled chunk
// layout [bh][ch=32][32768B], inner = (c*64 + kl*2) ^ ((c&7)<<4).
// ---------------------------------------------------------------------------
__global__ __launch_bounds__(256) void k_vt_split(
    const float* __restrict__ va, char* __restrict__ vthi,
    char* __restrict__ vtlo)
{
  const int s0 = blockIdx.x * 64, c0 = blockIdx.y * 64, bh = blockIdx.z;
  const int tid = threadIdx.x;
  __shared__ __align__(16) float T[64][68];
#pragma unroll
  for (int j = 0; j < 16; ++j) {
    const int idx = tid + 256 * j;
    const int sl = idx >> 4, c4 = (idx & 15) * 4;
    *(float4*)&T[sl][c4] =
        *(const float4*)&va[((size_t)bh * S_ + s0 + sl) * 512 + c0 + c4];
  }
  __syncthreads();
#pragma unroll
  for (int j = 0; j < 2; ++j) {
    const int idx = tid + 256 * j;
    const int cl = idx >> 3, sub = idx & 7;
    const int c = c0 + cl;
    float v[8];
#pragma unroll
    for (int jj = 0; jj < 8; ++jj) v[jj] = T[sub * 8 + jj][cl];
    unsigned hw[4], lw[4];
#pragma unroll
    for (int p = 0; p < 4; ++p) {
      const float a = v[2 * p], bb = v[2 * p + 1];
      const unsigned h = cvt_pk_bf16(a, bb);
      const float ra = a - __uint_as_float(h << 16);
      const float rb = bb - __uint_as_float(h & 0xffff0000u);
      hw[p] = h;
      lw[p] = cvt_pk_bf16(ra, rb);
    }
    const int ch = (s0 >> 5) + (sub >> 2);
    const int part = sub & 3;
    const unsigned inner = (unsigned)((c * 64 + part * 16) ^ ((c & 7) << 4));
    const size_t off = (size_t)bh * 1048576 + (size_t)ch * 32768 + inner;
    *(uint4*)(vthi + off) = make_uint4(hw[0], hw[1], hw[2], hw[3]);
    *(uint4*)(vtlo + off) = make_uint4(lw[0], lw[1], lw[2], lw[3]);
  }
}

// ---------------------------------------------------------------------------
// MFMA flash attention. Block = (bh, 64 q rows). 4 waves: w = qw*2+cw;
// wave owns q rows qbase+qw*32..+31 and PV cols cw*256..+255.
// Chunk = 32 k. Scores: C = mfma(A=K[32k x 128f], B=Q[128f x 32q]) split 3x.
// Softmax wave-local (defer-max THR=8). P repacked in-register to A-frags.
// PV: acc[cf] += mfma(A=P, B=V) split 3x. ao[b][s][m][h*64+dd].
// ---------------------------------------------------------------------------
__global__ __launch_bounds__(256, 1) void k_flash(
    const unsigned short* __restrict__ qrh, const unsigned short* __restrict__ qrl,
    const char* __restrict__ krh, const char* __restrict__ krl,
    const char* __restrict__ vthi, const char* __restrict__ vtlo,
    float* __restrict__ ao)
{
  extern __shared__ char sm[];
  char* Vhi = sm;                 // 32KB
  char* Vlo = sm + 32768;         // 32KB
  char* Khi = sm + 65536;         // 8KB
  char* Klo = sm + 73728;         // 8KB

  const int tid = threadIdx.x;
  const int w = tid >> 6, lane = tid & 63;
  const int lrow = lane & 31, lhi = lane >> 5;
  const int qw = w >> 1, cw = w & 1;

  const int phys = blockIdx.x;
  const int bh = ((phys & 7) << 1) | ((phys >> 3) & 1);  // XCD-local bh
  const int qb = phys >> 4;
  const int b = bh >> 3, h = bh & 7;
  const int qbase = qb * 64 + qw * 32;

  // Q fragments in registers (natural layout reads)
  uint4 qfh[8], qfl[8];
  {
    const size_t rowb = ((size_t)bh * S_ + qbase + lrow) * 128;
#pragma unroll
    for (int fs = 0; fs < 8; ++fs) {
      const size_t e = rowb + fs * 16 + lhi * 8;
      qfh[fs] = *(const uint4*)(qrh + e);
      qfl[fs] = *(const uint4*)(qrl + e);
    }
  }

  const char* vh_c = vthi + (size_t)bh * 1048576;
  const char* vl_c = vtlo + (size_t)bh * 1048576;
  const char* kh_c = krh + (size_t)bh * 262144;
  const char* kl_c = krl + (size_t)bh * 262144;

  f32x16 acc[8];
#pragma unroll
  for (int i = 0; i < 8; ++i)
#pragma unroll
    for (int r = 0; r < 16; ++r) acc[i][r] = 0.f;
  float m_run = -1e30f, l_run = 0.f;

  for (int ch = 0; ch < 32; ++ch) {
    // ---- stage chunk: V (64KB hi+lo) + K (16KB hi+lo), all linear copies ----
    {
      const char* gh = vh_c + (size_t)ch * 32768;
      const char* gl = vl_c + (size_t)ch * 32768;
#pragma unroll
      for (int i = 0; i < 8; ++i) {
        __builtin_amdgcn_global_load_lds(gh + i * 4096 + tid * 16, Vhi + i * 4096 + w * 1024, 16, 0, 0);
        __builtin_amdgcn_global_load_lds(gl + i * 4096 + tid * 16, Vlo + i * 4096 + w * 1024, 16, 0, 0);
      }
      const char* gkh = kh_c + (size_t)ch * 8192;
      const char* gkl = kl_c + (size_t)ch * 8192;
#pragma unroll
      for (int i = 0; i < 2; ++i) {
        __builtin_amdgcn_global_load_lds(gkh + i * 4096 + tid * 16, Khi + i * 4096 + w * 1024, 16, 0, 0);
        __builtin_amdgcn_global_load_lds(gkl + i * 4096 + tid * 16, Klo + i * 4096 + w * 1024, 16, 0, 0);
      }
    }
    __syncthreads();

    // ---- scores: S[32k x 32q] ----
    f32x16 s;
#pragma unroll
    for (int r = 0; r < 16; ++r) s[r] = 0.f;
#pragma unroll
    for (int fs = 0; fs < 8; ++fs) {
      const unsigned kaddr = (unsigned)((lrow * 256 + fs * 32 + lhi * 16) ^ ((lrow & 7) << 4));
      U4B8 kh, kl2, qh, ql;
      kh.u  = *(const uint4*)(Khi + kaddr);
      kl2.u = *(const uint4*)(Klo + kaddr);
      qh.u = qfh[fs]; ql.u = qfl[fs];
      s = __builtin_amdgcn_mfma_f32_32x32x16_bf16(kh.v,  qh.v, s, 0, 0, 0);
      s = __builtin_amdgcn_mfma_f32_32x32x16_bf16(kl2.v, qh.v, s, 0, 0, 0);
      s = __builtin_amdgcn_mfma_f32_32x32x16_bf16(kh.v,  ql.v, s, 0, 0, 0);
    }

    // ---- online softmax (per q = lrow), defer-max ----
    float mx = s[0];
#pragma unroll
    for (int r = 1; r < 16; ++r) mx = fmaxf(mx, s[r]);
    mx = fmaxf(mx, __shfl_xor(mx, 32));
    if (!__all(mx <= m_run + 8.f)) {
      const float mnew = fmaxf(m_run, mx);
      const float sc = __expf(m_run - mnew);
      float scr[16];
#pragma unroll
      for (int r = 0; r < 16; ++r)
        scr[r] = __shfl(sc, (r & 3) + 8 * (r >> 2) + 4 * lhi);
#pragma unroll
      for (int i = 0; i < 8; ++i)
#pragma unroll
        for (int r = 0; r < 16; ++r) acc[i][r] *= scr[r];
      l_run *= sc;
      m_run = mnew;
    }
    float p[16];
#pragma unroll
    for (int r = 0; r < 16; ++r) p[r] = __expf(s[r] - m_run);
    float rs = 0.f;
#pragma unroll
    for (int r = 0; r < 16; ++r) rs += p[r];
    rs += __shfl_xor(rs, 32);
    l_run += rs;

    // ---- repack P (hi & lo splits) to PV A-fragments ----
    unsigned wh[8], wl[8];
#pragma unroll
    for (int i = 0; i < 8; ++i) {
      const float a = p[2 * i], c2 = p[2 * i + 1];
      const unsigned hw = cvt_pk_bf16(a, c2);
      const float ra = a - __uint_as_float(hw << 16);
      const float rc = c2 - __uint_as_float(hw & 0xffff0000u);
      wh[i] = hw;
      wl[i] = cvt_pk_bf16(ra, rc);
    }
    // cross-half exchange: word_lo = hi? partner(hi_w) : lo_w ; word_hi = hi? hi_w : partner(lo_w)
    auto mix = [&](unsigned &lo_w, unsigned &hi_w) {
      const unsigned s_lo = (unsigned)__shfl_xor((int)lo_w, 32);
      const unsigned s_hi = (unsigned)__shfl_xor((int)hi_w, 32);
      const unsigned wlo = lhi ? s_hi : lo_w;
      const unsigned whi = lhi ? hi_w : s_lo;
      lo_w = wlo; hi_w = whi;
    };
    mix(wh[0], wh[2]); mix(wh[1], wh[3]); mix(wh[4], wh[6]); mix(wh[5], wh[7]);
    mix(wl[0], wl[2]); mix(wl[1], wl[3]); mix(wl[4], wl[6]); mix(wl[5], wl[7]);
    U4B8 pah0, pah1, pal0, pal1;
    pah0.u = make_uint4(wh[0], wh[1], wh[2], wh[3]);
    pah1.u = make_uint4(wh[4], wh[5], wh[6], wh[7]);
    pal0.u = make_uint4(wl[0], wl[1], wl[2], wl[3]);
    pal1.u = make_uint4(wl[4], wl[5], wl[6], wl[7]);

    // ---- PV ----
#pragma unroll
    for (int ks = 0; ks < 2; ++ks) {
      const U4B8 &pa_h = ks ? pah1 : pah0;
      const U4B8 &pa_l = ks ? pal1 : pal0;
#pragma unroll
      for (int cf = 0; cf < 8; ++cf) {
        const int c = cw * 256 + cf * 32 + lrow;
        const unsigned vaddr = (unsigned)((c * 64 + ks * 32 + lhi * 16) ^ ((c & 7) << 4));
        U4B8 vh, vl2;
        vh.u  = *(const uint4*)(Vhi + vaddr);
        vl2.u = *(const uint4*)(Vlo + vaddr);
        acc[cf] = __builtin_amdgcn_mfma_f32_32x32x16_bf16(pa_h.v, vh.v,  acc[cf], 0, 0, 0);
        acc[cf] = __builtin_amdgcn_mfma_f32_32x32x16_bf16(pa_l.v, vh.v,  acc[cf], 0, 0, 0);
        acc[cf] = __builtin_amdgcn_mfma_f32_32x32x16_bf16(pa_h.v, vl2.v, acc[cf], 0, 0, 0);
      }
    }
    __syncthreads();
  }

  // ---- epilogue: normalize + store ----
  const float linv = 1.0f / l_run;
  float lr[16];
#pragma unroll
  for (int r = 0; r < 16; ++r)
    lr[r] = __shfl(linv, (r & 3) + 8 * (r >> 2) + 4 * lhi);
#pragma unroll
  for (int cf = 0; cf < 8; ++cf) {
    const int c = cw * 256 + cf * 32 + lrow;
    const int m = c >> 6, dd = c & 63;
#pragma unroll
    for (int r = 0; r < 16; ++r) {
      const int qr = (r & 3) + 8 * (r >> 2) + 4 * lhi;
      const int srow = qbase + qr;
      const size_t off = (((size_t)(b * S_ + srow)) * 8 + m) * 512 + h * 64 + dd;
      ao[off] = acc[cf][r] * lr[r];
    }
  }
}

// ---------------------------------------------------------------------------
// out_atoms = ao @ Wo^T + fused log-weight delta (unchanged).
// ---------------------------------------------------------------------------
__global__ __launch_bounds__(256) void k_out(
    const float* __restrict__ ao, const float* __restrict__ Wo,
    const float* __restrict__ Ww, const float* __restrict__ qlw,
    float* __restrict__ out)
{
  const int s2 = blockIdx.x;
  const int b = blockIdx.z;
  const int s0 = s2 * 2;
  const int tid = threadIdx.x, w = tid >> 6, lane = tid & 63;

  __shared__ __align__(16) float As[16 * 512];
  __shared__ __align__(16) float WoS[64 * 65];
  __shared__ float Os[16 * 64];

  const float* abase = ao + (size_t)((b * S_ + s0) * 8) * 512;
#pragma unroll
  for (int j = 0; j < 8; ++j) {
    const int i = tid + 256 * j;
    *(float4*)&As[4 * i] = *(const float4*)&abase[4 * i];
  }
  float acc[4] = {0.f, 0.f, 0.f, 0.f};
  for (int ft = 0; ft < 8; ++ft) {
    __syncthreads();
    for (int i = tid; i < 4096; i += 256) {
      const int dwo = i >> 6, fi = i & 63;
      WoS[fi * 65 + dwo] = Wo[dwo * 512 + ft * 64 + fi];
    }
    __syncthreads();
#pragma unroll 8
    for (int fi = 0; fi < 64; ++fi) {
      const float wv = WoS[fi * 65 + lane];
      const int f = ft * 64 + fi;
#pragma unroll
      for (int ri = 0; ri < 4; ++ri)
        acc[ri] = fmaf(As[(w * 4 + ri) * 512 + f], wv, acc[ri]);
    }
  }
#pragma unroll
  for (int ri = 0; ri < 4; ++ri) {
    const int row = w * 4 + ri;
    const int R = (b * S_ + s0) * 8 + row;
    out[(size_t)R * 64 + lane] = acc[ri];
    Os[row * 64 + lane] = acc[ri];
  }
  __syncthreads();
  if (w < 2) {
    float mean = 0.f;
#pragma unroll
    for (int m = 0; m < 8; ++m) mean += Os[(w * 8 + m) * 64 + lane];
    mean *= 0.125f;
    float dsel = 0.f;
#pragma unroll
    for (int mw = 0; mw < 8; ++mw) {
      float part = mean * Ww[mw * 64 + lane];
      part += __shfl_xor(part, 1);
      part += __shfl_xor(part, 2);
      part += __shfl_xor(part, 4);
      part += __shfl_xor(part, 8);
      part += __shfl_xor(part, 16);
      part += __shfl_xor(part, 32);
      if (lane == mw) dsel = part;
    }
    if (lane < 8) {
      const int idx = (b * S_ + s0 + w) * 8 + lane;
      out[1048576 + idx] = qlw[idx] + dsel;
    }
  }
}

// ---------------------------------------------------------------------------
extern "C" void kernel_launch(void* const* d_in, const int* in_sizes, int n_in,
                              void* d_out, int out_size, void* d_ws, size_t ws_size,
                              hipStream_t stream)
{
  const float* q_atoms = (const float*)d_in[0];
  const float* q_logw  = (const float*)d_in[1];
  const float* k_atoms = (const float*)d_in[2];
  const float* k_logw  = (const float*)d_in[3];
  const float* v_atoms = (const float*)d_in[4];
  const float* cosT  = (const float*)d_in[6];
  const float* sinT  = (const float*)d_in[7];
  const float* Wq    = (const float*)d_in[8];
  const float* Wk    = (const float*)d_in[9];
  const float* Wv    = (const float*)d_in[10];
  const float* Wo    = (const float*)d_in[11];
  const float* Ww    = (const float*)d_in[12];
  const float* logbw = (const float*)d_in[13];
  const float* rffb  = (const float*)d_in[14];
  float* out = (float*)d_out;

  char* wsb = (char*)d_ws;
  char* qrh = wsb;
  char* qrl = wsb + (4u << 20);
  char* krh = wsb + (8u << 20);
  char* krl = wsb + (12u << 20);
  float* va = (float*)(wsb + (16u << 20));   // 32MB, reused as ao
  float* ao = va;
  char* vthi = wsb + (48u << 20);
  char* vtlo = wsb + (64u << 20);

  const dim3 blk(256);
  k_proj_rff<<<dim3(128, 8, 2), blk, 0, stream>>>(q_atoms, q_logw, Wq, rffb, logbw, cosT, sinT, qrh, qrl, 0);
  k_proj_rff<<<dim3(128, 8, 2), blk, 0, stream>>>(k_atoms, k_logw, Wk, rffb, logbw, cosT, sinT, krh, krl, 1);
  k_proj_v  <<<dim3(128, 8, 2), blk, 0, stream>>>(v_atoms, Wv, va);
  k_vt_split<<<dim3(16, 8, 16), blk, 0, stream>>>(va, vthi, vtlo);
  k_flash   <<<dim3(256), blk, 81920, stream>>>((const unsigned short*)qrh, (const unsigned short*)qrl,
                                                krh, krl, vthi, vtlo, ao);
  k_out     <<<dim3(512, 1, 2), blk, 0, stream>>>(ao, Wo, Ww, q_logw, out);
}

// Round 3
// 328.230 us; speedup vs baseline: 2.9756x; 1.0046x over previous
//
#include <hip/hip_runtime.h>
#include <math.h>

// KME attention. B=2 S=1024 M=8 D=64 H=8 NF=64
// Round 3: k_flash restructured for 2 blocks/CU (48KB LDS, V half-chunk
// staging, setprio); k_vt_split fused into k_proj_v (direct split/transposed/
// swizzled V write).
//
// ws layout (bytes), 80 MiB total:
//   qrh  @ 0MB   4MB  ushort [bh][s][128]          (natural)
//   qrl  @ 4MB   4MB
//   krh  @ 8MB   4MB  swizzled-chunk layout [bh][ch=32][8192B]
//   krl  @12MB   4MB
//   vthi @16MB  16MB  [bh][ch=32][half=2][16KB], inner=(c*32+p2*16)^(((c>>2)&7)<<4)
//   vtlo @32MB  16MB
//   ao   @48MB  32MB  f32 [b][s][m][512]

#define B_ 2
#define S_ 1024
#define H_ 8

typedef __attribute__((ext_vector_type(8))) short short8;
typedef __attribute__((ext_vector_type(16))) float f32x16;
union U4B8 { uint4 u; short8 v; };

__device__ inline unsigned cvt_pk_bf16(float a, float b) {
  unsigned r;
  asm("v_cvt_pk_bf16_f32 %0, %1, %2" : "=v"(r) : "v"(a), "v"(b));
  return r;
}
__device__ inline void bsplit(float v, unsigned short &h, unsigned short &l) {
  unsigned hw = cvt_pk_bf16(v, 0.f);
  float hf = __uint_as_float(hw << 16);
  unsigned lw = cvt_pk_bf16(v - hf, 0.f);
  h = (unsigned short)hw; l = (unsigned short)lw;
}

// ---------------------------------------------------------------------------
// Fused projection + RoPE + RFF encode (+ softmax-weighted sum over m).
// Writes bf16 hi/lo planes. kswz=0: natural [bh][s][128].
// kswz=1: swizzled-chunk layout for k_flash's linear global_load_lds staging.
// ---------------------------------------------------------------------------
__global__ __launch_bounds__(256) void k_proj_rff(
    const float* __restrict__ atoms, const float* __restrict__ logw,
    const float* __restrict__ W, const float* __restrict__ freqb,
    const float* __restrict__ logbw, const float* __restrict__ cosT,
    const float* __restrict__ sinT, char* __restrict__ oh,
    char* __restrict__ ol, int kswz)
{
  const int s0 = blockIdx.x * 8;
  const int h  = blockIdx.y;
  const int b  = blockIdx.z;
  const int tid = threadIdx.x;
  const int w = tid >> 6, lane = tid & 63;

  __shared__ __align__(16) float Wt[64 * 65];
  __shared__ __align__(16) float Fq[64 * 64];
  __shared__ __align__(16) float As[8 * 8 * 64];
  __shared__ __align__(16) float Qa[64 * 64];
  __shared__ __align__(16) float Cs[8 * 64];
  __shared__ __align__(16) float Sn[8 * 64];
  __shared__ float Wm[8 * 8];

  const float fscale = __expf(-logbw[h]);
  for (int i = tid; i < 4096; i += 256) {
    const int dd = i >> 6, d = i & 63;
    Wt[d * 65 + dd] = W[h * 4096 + i];
    Fq[i] = freqb[h * 4096 + i] * fscale;
  }
  for (int i = tid; i < 4096; i += 256)
    As[i] = atoms[(size_t)(b * S_ + s0) * 512 + i];
  for (int i = tid; i < 512; i += 256) {
    const int sl = i >> 6, d = i & 63;
    Cs[i] = cosT[(s0 + sl) * 64 + d];
    Sn[i] = sinT[(s0 + sl) * 64 + d];
  }
  if (tid < 8) {
    const float* lw = logw + (size_t)(b * S_ + s0 + tid) * 8;
    float mx = lw[0];
    for (int m = 1; m < 8; ++m) mx = fmaxf(mx, lw[m]);
    float e[8], sum = 0.f;
    for (int m = 0; m < 8; ++m) { e[m] = __expf(lw[m] - mx); sum += e[m]; }
    const float inv = 1.0f / sum;
    for (int m = 0; m < 8; ++m) Wm[tid * 8 + m] = e[m] * inv;
  }
  __syncthreads();

  float acc[16];
#pragma unroll
  for (int i = 0; i < 16; ++i) acc[i] = 0.f;
#pragma unroll
  for (int d4 = 0; d4 < 16; ++d4) {
    const float w0 = Wt[(4 * d4 + 0) * 65 + lane];
    const float w1 = Wt[(4 * d4 + 1) * 65 + lane];
    const float w2 = Wt[(4 * d4 + 2) * 65 + lane];
    const float w3 = Wt[(4 * d4 + 3) * 65 + lane];
#pragma unroll
    for (int smi = 0; smi < 16; ++smi) {
      const float4 a = *(const float4*)&As[(w * 16 + smi) * 64 + 4 * d4];
      acc[smi] = fmaf(a.x, w0, fmaf(a.y, w1, fmaf(a.z, w2, fmaf(a.w, w3, acc[smi]))));
    }
  }
#pragma unroll
  for (int smi = 0; smi < 16; ++smi) {
    const int sm = w * 16 + smi, sl = sm >> 3;
    const float other = __shfl_xor(acc[smi], 32);
    const float rot = (lane < 32) ? -other : other;
    Qa[sm * 64 + lane] = acc[smi] * Cs[sl * 64 + lane] + rot * Sn[sl * 64 + lane];
  }

  float pr[16];
#pragma unroll
  for (int i = 0; i < 16; ++i) pr[i] = 0.f;
#pragma unroll
  for (int d4 = 0; d4 < 16; ++d4) {
    const float f0 = Fq[(4 * d4 + 0) * 64 + lane];
    const float f1 = Fq[(4 * d4 + 1) * 64 + lane];
    const float f2 = Fq[(4 * d4 + 2) * 64 + lane];
    const float f3 = Fq[(4 * d4 + 3) * 64 + lane];
#pragma unroll
    for (int smi = 0; smi < 16; ++smi) {
      const float4 a = *(const float4*)&Qa[(w * 16 + smi) * 64 + 4 * d4];
      pr[smi] = fmaf(a.x, f0, fmaf(a.y, f1, fmaf(a.z, f2, fmaf(a.w, f3, pr[smi]))));
    }
  }
  float oc0 = 0.f, os0 = 0.f, oc1 = 0.f, os1 = 0.f;
#pragma unroll
  for (int smi = 0; smi < 16; ++smi) {
    const int sm = w * 16 + smi, sl = sm >> 3, m = sm & 7;
    float sv, cv;
    __sincosf(pr[smi], &sv, &cv);
    const float wt = Wm[sl * 8 + m];
    if (smi < 8) { oc0 = fmaf(wt, cv, oc0); os0 = fmaf(wt, sv, os0); }
    else         { oc1 = fmaf(wt, cv, oc1); os1 = fmaf(wt, sv, os1); }
  }
  const int sA = s0 + w * 2;
  const int bh = b * H_ + h;
  if (!kswz) {
    size_t e0 = ((size_t)bh * S_ + sA) * 128 + lane;
    unsigned short hh, ll;
    bsplit(oc0 * 0.125f, hh, ll); ((unsigned short*)oh)[e0] = hh;       ((unsigned short*)ol)[e0] = ll;
    bsplit(os0 * 0.125f, hh, ll); ((unsigned short*)oh)[e0 + 64] = hh;  ((unsigned short*)ol)[e0 + 64] = ll;
    bsplit(oc1 * 0.125f, hh, ll); ((unsigned short*)oh)[e0 + 128] = hh; ((unsigned short*)ol)[e0 + 128] = ll;
    bsplit(os1 * 0.125f, hh, ll); ((unsigned short*)oh)[e0 + 192] = hh; ((unsigned short*)ol)[e0 + 192] = ll;
  } else {
    auto put = [&](int s, int f, float v) {
      const int ch = s >> 5, klr = s & 31;
      const unsigned inner = (unsigned)(((klr << 8) + (f << 1)) ^ ((klr & 7) << 4));
      const size_t off = (size_t)bh * 262144 + (size_t)ch * 8192 + inner;
      unsigned short hh, ll; bsplit(v, hh, ll);
      *(unsigned short*)(oh + off) = hh;
      *(unsigned short*)(ol + off) = ll;
    };
    put(sA,     lane,      oc0 * 0.125f);
    put(sA,     64 + lane, os0 * 0.125f);
    put(sA + 1, lane,      oc1 * 0.125f);
    put(sA + 1, 64 + lane, os1 * 0.125f);
  }
}

// ---------------------------------------------------------------------------
// V projection fused with split/transpose/swizzle write.
// Block = (b, h, 8 s). The 8 s rows form exactly one 16B k-group of the
// half-chunk layout: ch = s0>>5, half = (s0>>4)&1, part2 = (s0>>3)&1.
// vt inner = (c*32 + part2*16) ^ (((c>>2)&7)<<4), c = m*64+dd.
// ---------------------------------------------------------------------------
__global__ __launch_bounds__(256) void k_proj_v(
    const float* __restrict__ atoms, const float* __restrict__ W,
    char* __restrict__ vthi, char* __restrict__ vtlo)
{
  const int s0 = blockIdx.x * 8;
  const int h  = blockIdx.y;
  const int b  = blockIdx.z;
  const int tid = threadIdx.x;
  const int w = tid >> 6, lane = tid & 63;

  __shared__ __align__(16) float Wt[64 * 65];
  __shared__ __align__(16) float As[8 * 8 * 64];
  __shared__ __align__(16) float T[8 * 517];

  for (int i = tid; i < 4096; i += 256) {
    const int dd = i >> 6, d = i & 63;
    Wt[d * 65 + dd] = W[h * 4096 + i];
  }
  for (int i = tid; i < 4096; i += 256)
    As[i] = atoms[(size_t)(b * S_ + s0) * 512 + i];
  __syncthreads();

  float acc[16];
#pragma unroll
  for (int i = 0; i < 16; ++i) acc[i] = 0.f;
#pragma unroll
  for (int d4 = 0; d4 < 16; ++d4) {
    const float w0 = Wt[(4 * d4 + 0) * 65 + lane];
    const float w1 = Wt[(4 * d4 + 1) * 65 + lane];
    const float w2 = Wt[(4 * d4 + 2) * 65 + lane];
    const float w3 = Wt[(4 * d4 + 3) * 65 + lane];
#pragma unroll
    for (int smi = 0; smi < 16; ++smi) {
      const float4 a = *(const float4*)&As[(w * 16 + smi) * 64 + 4 * d4];
      acc[smi] = fmaf(a.x, w0, fmaf(a.y, w1, fmaf(a.z, w2, fmaf(a.w, w3, acc[smi]))));
    }
  }
  // T[s_rel][c]: s_rel = w*2 + (smi>>3), c = (smi&7)*64 + lane
#pragma unroll
  for (int smi = 0; smi < 16; ++smi)
    T[(w * 2 + (smi >> 3)) * 517 + (smi & 7) * 64 + lane] = acc[smi];
  __syncthreads();

  const int bh = b * H_ + h;
  const int ch = s0 >> 5, half = (s0 >> 4) & 1, part2 = (s0 >> 3) & 1;
  const size_t base = (size_t)bh * 1048576 + (size_t)ch * 32768 + half * 16384;
#pragma unroll
  for (int j = 0; j < 2; ++j) {
    const int c = tid + j * 256;
    float v[8];
#pragma unroll
    for (int s = 0; s < 8; ++s) v[s] = T[s * 517 + c];
    unsigned hw[4], lw[4];
#pragma unroll
    for (int p = 0; p < 4; ++p) {
      const float a = v[2 * p], bb = v[2 * p + 1];
      const unsigned hword = cvt_pk_bf16(a, bb);
      const float ra = a - __uint_as_float(hword << 16);
      const float rb = bb - __uint_as_float(hword & 0xffff0000u);
      hw[p] = hword;
      lw[p] = cvt_pk_bf16(ra, rb);
    }
    const unsigned inner = (unsigned)((c * 32 + part2 * 16) ^ (((c >> 2) & 7) << 4));
    *(uint4*)(vthi + base + inner) = make_uint4(hw[0], hw[1], hw[2], hw[3]);
    *(uint4*)(vtlo + base + inner) = make_uint4(lw[0], lw[1], lw[2], lw[3]);
  }
}

// ---------------------------------------------------------------------------
// MFMA flash attention. Block = (bh, 64 q rows). 4 waves: w = qw*2+cw.
// Chunk = 32 k; V staged in 16-k half-chunks (LDS 48KB -> 2 blocks/CU).
// ---------------------------------------------------------------------------
__global__ __launch_bounds__(256, 2) void k_flash(
    const unsigned short* __restrict__ qrh, const unsigned short* __restrict__ qrl,
    const char* __restrict__ krh, const char* __restrict__ krl,
    const char* __restrict__ vthi, const char* __restrict__ vtlo,
    float* __restrict__ ao)
{
  extern __shared__ char sm[];
  char* Vhi = sm;                 // 16KB (one half-chunk, hi)
  char* Vlo = sm + 16384;         // 16KB
  char* Khi = sm + 32768;         // 8KB
  char* Klo = sm + 40960;         // 8KB

  const int tid = threadIdx.x;
  const int w = tid >> 6, lane = tid & 63;
  const int lrow = lane & 31, lhi = lane >> 5;
  const int qw = w >> 1, cw = w & 1;

  const int phys = blockIdx.x;
  const int bh = ((phys & 7) << 1) | ((phys >> 3) & 1);  // XCD-local bh
  const int qb = phys >> 4;
  const int b = bh >> 3, h = bh & 7;
  const int qbase = qb * 64 + qw * 32;

  // Q fragments in registers
  uint4 qfh[8], qfl[8];
  {
    const size_t rowb = ((size_t)bh * S_ + qbase + lrow) * 128;
#pragma unroll
    for (int fs = 0; fs < 8; ++fs) {
      const size_t e = rowb + fs * 16 + lhi * 8;
      qfh[fs] = *(const uint4*)(qrh + e);
      qfl[fs] = *(const uint4*)(qrl + e);
    }
  }

  const char* vh_c = vthi + (size_t)bh * 1048576;
  const char* vl_c = vtlo + (size_t)bh * 1048576;
  const char* kh_c = krh + (size_t)bh * 262144;
  const char* kl_c = krl + (size_t)bh * 262144;

  // staging helpers: linear 16B-per-lane copies
  auto issue_v = [&](int ch, int half) {
    const size_t g = (size_t)ch * 32768 + half * 16384;
#pragma unroll
    for (int i = 0; i < 4; ++i) {
      __builtin_amdgcn_global_load_lds(vh_c + g + i * 4096 + tid * 16, Vhi + i * 4096 + w * 1024, 16, 0, 0);
      __builtin_amdgcn_global_load_lds(vl_c + g + i * 4096 + tid * 16, Vlo + i * 4096 + w * 1024, 16, 0, 0);
    }
  };
  auto issue_k = [&](int ch) {
    const size_t g = (size_t)ch * 8192;
#pragma unroll
    for (int i = 0; i < 2; ++i) {
      __builtin_amdgcn_global_load_lds(kh_c + g + i * 4096 + tid * 16, Khi + i * 4096 + w * 1024, 16, 0, 0);
      __builtin_amdgcn_global_load_lds(kl_c + g + i * 4096 + tid * 16, Klo + i * 4096 + w * 1024, 16, 0, 0);
    }
  };

  f32x16 acc[8];
#pragma unroll
  for (int i = 0; i < 8; ++i)
#pragma unroll
    for (int r = 0; r < 16; ++r) acc[i][r] = 0.f;
  float m_run = -1e30f, l_run = 0.f;

  issue_v(0, 0);
  issue_k(0);

  for (int ch = 0; ch < 32; ++ch) {
    __syncthreads();   // Vhalf0(ch) + K(ch) ready

    // ---- scores: S[32k x 32q] ----
    f32x16 s;
#pragma unroll
    for (int r = 0; r < 16; ++r) s[r] = 0.f;
    __builtin_amdgcn_s_setprio(1);
#pragma unroll
    for (int fs = 0; fs < 8; ++fs) {
      const unsigned kaddr = (unsigned)((lrow * 256 + fs * 32 + lhi * 16) ^ ((lrow & 7) << 4));
      U4B8 kh, kl2, qh, ql;
      kh.u  = *(const uint4*)(Khi + kaddr);
      kl2.u = *(const uint4*)(Klo + kaddr);
      qh.u = qfh[fs]; ql.u = qfl[fs];
      s = __builtin_amdgcn_mfma_f32_32x32x16_bf16(kh.v,  qh.v, s, 0, 0, 0);
      s = __builtin_amdgcn_mfma_f32_32x32x16_bf16(kl2.v, qh.v, s, 0, 0, 0);
      s = __builtin_amdgcn_mfma_f32_32x32x16_bf16(kh.v,  ql.v, s, 0, 0, 0);
    }
    __builtin_amdgcn_s_setprio(0);

    // ---- online softmax (per q = lrow), defer-max ----
    float mx = s[0];
#pragma unroll
    for (int r = 1; r < 16; ++r) mx = fmaxf(mx, s[r]);
    mx = fmaxf(mx, __shfl_xor(mx, 32));
    if (!__all(mx <= m_run + 8.f)) {
      const float mnew = fmaxf(m_run, mx);
      const float sc = __expf(m_run - mnew);
      float scr[16];
#pragma unroll
      for (int r = 0; r < 16; ++r)
        scr[r] = __shfl(sc, (r & 3) + 8 * (r >> 2) + 4 * lhi);
#pragma unroll
      for (int i = 0; i < 8; ++i)
#pragma unroll
        for (int r = 0; r < 16; ++r) acc[i][r] *= scr[r];
      l_run *= sc;
      m_run = mnew;
    }
    float p[16];
#pragma unroll
    for (int r = 0; r < 16; ++r) p[r] = __expf(s[r] - m_run);
    float rs = 0.f;
#pragma unroll
    for (int r = 0; r < 16; ++r) rs += p[r];
    rs += __shfl_xor(rs, 32);
    l_run += rs;

    // ---- repack P (hi & lo splits) to PV A-fragments ----
    unsigned wh[8], wl[8];
#pragma unroll
    for (int i = 0; i < 8; ++i) {
      const float a = p[2 * i], c2 = p[2 * i + 1];
      const unsigned hword = cvt_pk_bf16(a, c2);
      const float ra = a - __uint_as_float(hword << 16);
      const float rc = c2 - __uint_as_float(hword & 0xffff0000u);
      wh[i] = hword;
      wl[i] = cvt_pk_bf16(ra, rc);
    }
    auto mix = [&](unsigned &lo_w, unsigned &hi_w) {
      const unsigned s_lo = (unsigned)__shfl_xor((int)lo_w, 32);
      const unsigned s_hi = (unsigned)__shfl_xor((int)hi_w, 32);
      const unsigned wlo = lhi ? s_hi : lo_w;
      const unsigned whi = lhi ? hi_w : s_lo;
      lo_w = wlo; hi_w = whi;
    };
    mix(wh[0], wh[2]); mix(wh[1], wh[3]); mix(wh[4], wh[6]); mix(wh[5], wh[7]);
    mix(wl[0], wl[2]); mix(wl[1], wl[3]); mix(wl[4], wl[6]); mix(wl[5], wl[7]);
    U4B8 pah0, pah1, pal0, pal1;
    pah0.u = make_uint4(wh[0], wh[1], wh[2], wh[3]);
    pah1.u = make_uint4(wh[4], wh[5], wh[6], wh[7]);
    pal0.u = make_uint4(wl[0], wl[1], wl[2], wl[3]);
    pal1.u = make_uint4(wl[4], wl[5], wl[6], wl[7]);

    // ---- PV half 0 (k 0..15 of chunk) ----
    __builtin_amdgcn_s_setprio(1);
#pragma unroll
    for (int cf = 0; cf < 8; ++cf) {
      const int c = cw * 256 + cf * 32 + lrow;
      const unsigned vaddr = (unsigned)((c * 32 + lhi * 16) ^ (((c >> 2) & 7) << 4));
      U4B8 vh, vl2;
      vh.u  = *(const uint4*)(Vhi + vaddr);
      vl2.u = *(const uint4*)(Vlo + vaddr);
      acc[cf] = __builtin_amdgcn_mfma_f32_32x32x16_bf16(pah0.v, vh.v,  acc[cf], 0, 0, 0);
      acc[cf] = __builtin_amdgcn_mfma_f32_32x32x16_bf16(pal0.v, vh.v,  acc[cf], 0, 0, 0);
      acc[cf] = __builtin_amdgcn_mfma_f32_32x32x16_bf16(pah0.v, vl2.v, acc[cf], 0, 0, 0);
    }
    __builtin_amdgcn_s_setprio(0);
    __syncthreads();   // all reads of Vhalf0 + K(ch) done

    issue_v(ch, 1);
    if (ch < 31) issue_k(ch + 1);
    __syncthreads();   // Vhalf1 ready

    // ---- PV half 1 (k 16..31 of chunk) ----
    __builtin_amdgcn_s_setprio(1);
#pragma unroll
    for (int cf = 0; cf < 8; ++cf) {
      const int c = cw * 256 + cf * 32 + lrow;
      const unsigned vaddr = (unsigned)((c * 32 + lhi * 16) ^ (((c >> 2) & 7) << 4));
      U4B8 vh, vl2;
      vh.u  = *(const uint4*)(Vhi + vaddr);
      vl2.u = *(const uint4*)(Vlo + vaddr);
      acc[cf] = __builtin_amdgcn_mfma_f32_32x32x16_bf16(pah1.v, vh.v,  acc[cf], 0, 0, 0);
      acc[cf] = __builtin_amdgcn_mfma_f32_32x32x16_bf16(pal1.v, vh.v,  acc[cf], 0, 0, 0);
      acc[cf] = __builtin_amdgcn_mfma_f32_32x32x16_bf16(pah1.v, vl2.v, acc[cf], 0, 0, 0);
    }
    __builtin_amdgcn_s_setprio(0);

    if (ch < 31) {
      __syncthreads();   // Vhalf1 reads done
      issue_v(ch + 1, 0);
    }
  }

  // ---- epilogue: normalize + store ----
  const float linv = 1.0f / l_run;
  float lr[16];
#pragma unroll
  for (int r = 0; r < 16; ++r)
    lr[r] = __shfl(linv, (r & 3) + 8 * (r >> 2) + 4 * lhi);
#pragma unroll
  for (int cf = 0; cf < 8; ++cf) {
    const int c = cw * 256 + cf * 32 + lrow;
    const int m = c >> 6, dd = c & 63;
#pragma unroll
    for (int r = 0; r < 16; ++r) {
      const int qr = (r & 3) + 8 * (r >> 2) + 4 * lhi;
      const int srow = qbase + qr;
      const size_t off = (((size_t)(b * S_ + srow)) * 8 + m) * 512 + h * 64 + dd;
      ao[off] = acc[cf][r] * lr[r];
    }
  }
}

// ---------------------------------------------------------------------------
// out_atoms = ao @ Wo^T + fused log-weight delta (unchanged).
// ---------------------------------------------------------------------------
__global__ __launch_bounds__(256) void k_out(
    const float* __restrict__ ao, const float* __restrict__ Wo,
    const float* __restrict__ Ww, const float* __restrict__ qlw,
    float* __restrict__ out)
{
  const int s2 = blockIdx.x;
  const int b = blockIdx.z;
  const int s0 = s2 * 2;
  const int tid = threadIdx.x, w = tid >> 6, lane = tid & 63;

  __shared__ __align__(16) float As[16 * 512];
  __shared__ __align__(16) float WoS[64 * 65];
  __shared__ float Os[16 * 64];

  const float* abase = ao + (size_t)((b * S_ + s0) * 8) * 512;
#pragma unroll
  for (int j = 0; j < 8; ++j) {
    const int i = tid + 256 * j;
    *(float4*)&As[4 * i] = *(const float4*)&abase[4 * i];
  }
  float acc[4] = {0.f, 0.f, 0.f, 0.f};
  for (int ft = 0; ft < 8; ++ft) {
    __syncthreads();
    for (int i = tid; i < 4096; i += 256) {
      const int dwo = i >> 6, fi = i & 63;
      WoS[fi * 65 + dwo] = Wo[dwo * 512 + ft * 64 + fi];
    }
    __syncthreads();
#pragma unroll 8
    for (int fi = 0; fi < 64; ++fi) {
      const float wv = WoS[fi * 65 + lane];
      const int f = ft * 64 + fi;
#pragma unroll
      for (int ri = 0; ri < 4; ++ri)
        acc[ri] = fmaf(As[(w * 4 + ri) * 512 + f], wv, acc[ri]);
    }
  }
#pragma unroll
  for (int ri = 0; ri < 4; ++ri) {
    const int row = w * 4 + ri;
    const int R = (b * S_ + s0) * 8 + row;
    out[(size_t)R * 64 + lane] = acc[ri];
    Os[row * 64 + lane] = acc[ri];
  }
  __syncthreads();
  if (w < 2) {
    float mean = 0.f;
#pragma unroll
    for (int m = 0; m < 8; ++m) mean += Os[(w * 8 + m) * 64 + lane];
    mean *= 0.125f;
    float dsel = 0.f;
#pragma unroll
    for (int mw = 0; mw < 8; ++mw) {
      float part = mean * Ww[mw * 64 + lane];
      part += __shfl_xor(part, 1);
      part += __shfl_xor(part, 2);
      part += __shfl_xor(part, 4);
      part += __shfl_xor(part, 8);
      part += __shfl_xor(part, 16);
      part += __shfl_xor(part, 32);
      if (lane == mw) dsel = part;
    }
    if (lane < 8) {
      const int idx = (b * S_ + s0 + w) * 8 + lane;
      out[1048576 + idx] = qlw[idx] + dsel;
    }
  }
}

// ---------------------------------------------------------------------------
extern "C" void kernel_launch(void* const* d_in, const int* in_sizes, int n_in,
                              void* d_out, int out_size, void* d_ws, size_t ws_size,
                              hipStream_t stream)
{
  const float* q_atoms = (const float*)d_in[0];
  const float* q_logw  = (const float*)d_in[1];
  const float* k_atoms = (const float*)d_in[2];
  const float* k_logw  = (const float*)d_in[3];
  const float* v_atoms = (const float*)d_in[4];
  const float* cosT  = (const float*)d_in[6];
  const float* sinT  = (const float*)d_in[7];
  const float* Wq    = (const float*)d_in[8];
  const float* Wk    = (const float*)d_in[9];
  const float* Wv    = (const float*)d_in[10];
  const float* Wo    = (const float*)d_in[11];
  const float* Ww    = (const float*)d_in[12];
  const float* logbw = (const float*)d_in[13];
  const float* rffb  = (const float*)d_in[14];
  float* out = (float*)d_out;

  char* wsb = (char*)d_ws;
  char* qrh = wsb;
  char* qrl = wsb + (4u << 20);
  char* krh = wsb + (8u << 20);
  char* krl = wsb + (12u << 20);
  char* vthi = wsb + (16u << 20);
  char* vtlo = wsb + (32u << 20);
  float* ao = (float*)(wsb + (48u << 20));

  const dim3 blk(256);
  k_proj_rff<<<dim3(128, 8, 2), blk, 0, stream>>>(q_atoms, q_logw, Wq, rffb, logbw, cosT, sinT, qrh, qrl, 0);
  k_proj_rff<<<dim3(128, 8, 2), blk, 0, stream>>>(k_atoms, k_logw, Wk, rffb, logbw, cosT, sinT, krh, krl, 1);
  k_proj_v  <<<dim3(128, 8, 2), blk, 0, stream>>>(v_atoms, Wv, vthi, vtlo);
  k_flash   <<<dim3(256), blk, 49152, stream>>>((const unsigned short*)qrh, (const unsigned short*)qrl,
                                                krh, krl, vthi, vtlo, ao);
  k_out     <<<dim3(512, 1, 2), blk, 0, stream>>>(ao, Wo, Ww, q_logw, out);
}

// Round 4
// 320.473 us; speedup vs baseline: 3.0476x; 1.0242x over previous
//
#include <hip/hip_runtime.h>
#include <math.h>

// KME attention. B=2 S=1024 M=8 D=64 H=8 NF=64
// Round 4: k_flash grid 256->512 (32 q-rows/block, 2 blocks/CU co-resident),
// acc halved to 4 frags (64 AGPR) so launch_bounds(256,2) fits w/o spill.
//
// ws layout (bytes), 80 MiB total:
//   qrh  @ 0MB   4MB  ushort [bh][s][128]          (natural)
//   qrl  @ 4MB   4MB
//   krh  @ 8MB   4MB  swizzled-chunk layout [bh][ch=32][8192B]
//   krl  @12MB   4MB
//   vthi @16MB  16MB  [bh][ch=32][half=2][16KB], inner=(c*32+p2*16)^(((c>>2)&7)<<4)
//   vtlo @32MB  16MB
//   ao   @48MB  32MB  f32 [b][s][m][512]

#define B_ 2
#define S_ 1024
#define H_ 8

typedef __attribute__((ext_vector_type(8))) short short8;
typedef __attribute__((ext_vector_type(16))) float f32x16;
union U4B8 { uint4 u; short8 v; };

__device__ inline unsigned cvt_pk_bf16(float a, float b) {
  unsigned r;
  asm("v_cvt_pk_bf16_f32 %0, %1, %2" : "=v"(r) : "v"(a), "v"(b));
  return r;
}
__device__ inline void bsplit(float v, unsigned short &h, unsigned short &l) {
  unsigned hw = cvt_pk_bf16(v, 0.f);
  float hf = __uint_as_float(hw << 16);
  unsigned lw = cvt_pk_bf16(v - hf, 0.f);
  h = (unsigned short)hw; l = (unsigned short)lw;
}

// ---------------------------------------------------------------------------
// Fused projection + RoPE + RFF encode (+ softmax-weighted sum over m).
// ---------------------------------------------------------------------------
__global__ __launch_bounds__(256) void k_proj_rff(
    const float* __restrict__ atoms, const float* __restrict__ logw,
    const float* __restrict__ W, const float* __restrict__ freqb,
    const float* __restrict__ logbw, const float* __restrict__ cosT,
    const float* __restrict__ sinT, char* __restrict__ oh,
    char* __restrict__ ol, int kswz)
{
  const int s0 = blockIdx.x * 8;
  const int h  = blockIdx.y;
  const int b  = blockIdx.z;
  const int tid = threadIdx.x;
  const int w = tid >> 6, lane = tid & 63;

  __shared__ __align__(16) float Wt[64 * 65];
  __shared__ __align__(16) float Fq[64 * 64];
  __shared__ __align__(16) float As[8 * 8 * 64];
  __shared__ __align__(16) float Qa[64 * 64];
  __shared__ __align__(16) float Cs[8 * 64];
  __shared__ __align__(16) float Sn[8 * 64];
  __shared__ float Wm[8 * 8];

  const float fscale = __expf(-logbw[h]);
  for (int i = tid; i < 4096; i += 256) {
    const int dd = i >> 6, d = i & 63;
    Wt[d * 65 + dd] = W[h * 4096 + i];
    Fq[i] = freqb[h * 4096 + i] * fscale;
  }
  for (int i = tid; i < 4096; i += 256)
    As[i] = atoms[(size_t)(b * S_ + s0) * 512 + i];
  for (int i = tid; i < 512; i += 256) {
    const int sl = i >> 6, d = i & 63;
    Cs[i] = cosT[(s0 + sl) * 64 + d];
    Sn[i] = sinT[(s0 + sl) * 64 + d];
  }
  if (tid < 8) {
    const float* lw = logw + (size_t)(b * S_ + s0 + tid) * 8;
    float mx = lw[0];
    for (int m = 1; m < 8; ++m) mx = fmaxf(mx, lw[m]);
    float e[8], sum = 0.f;
    for (int m = 0; m < 8; ++m) { e[m] = __expf(lw[m] - mx); sum += e[m]; }
    const float inv = 1.0f / sum;
    for (int m = 0; m < 8; ++m) Wm[tid * 8 + m] = e[m] * inv;
  }
  __syncthreads();

  float acc[16];
#pragma unroll
  for (int i = 0; i < 16; ++i) acc[i] = 0.f;
#pragma unroll
  for (int d4 = 0; d4 < 16; ++d4) {
    const float w0 = Wt[(4 * d4 + 0) * 65 + lane];
    const float w1 = Wt[(4 * d4 + 1) * 65 + lane];
    const float w2 = Wt[(4 * d4 + 2) * 65 + lane];
    const float w3 = Wt[(4 * d4 + 3) * 65 + lane];
#pragma unroll
    for (int smi = 0; smi < 16; ++smi) {
      const float4 a = *(const float4*)&As[(w * 16 + smi) * 64 + 4 * d4];
      acc[smi] = fmaf(a.x, w0, fmaf(a.y, w1, fmaf(a.z, w2, fmaf(a.w, w3, acc[smi]))));
    }
  }
#pragma unroll
  for (int smi = 0; smi < 16; ++smi) {
    const int sm = w * 16 + smi, sl = sm >> 3;
    const float other = __shfl_xor(acc[smi], 32);
    const float rot = (lane < 32) ? -other : other;
    Qa[sm * 64 + lane] = acc[smi] * Cs[sl * 64 + lane] + rot * Sn[sl * 64 + lane];
  }

  float pr[16];
#pragma unroll
  for (int i = 0; i < 16; ++i) pr[i] = 0.f;
#pragma unroll
  for (int d4 = 0; d4 < 16; ++d4) {
    const float f0 = Fq[(4 * d4 + 0) * 64 + lane];
    const float f1 = Fq[(4 * d4 + 1) * 64 + lane];
    const float f2 = Fq[(4 * d4 + 2) * 64 + lane];
    const float f3 = Fq[(4 * d4 + 3) * 64 + lane];
#pragma unroll
    for (int smi = 0; smi < 16; ++smi) {
      const float4 a = *(const float4*)&Qa[(w * 16 + smi) * 64 + 4 * d4];
      pr[smi] = fmaf(a.x, f0, fmaf(a.y, f1, fmaf(a.z, f2, fmaf(a.w, f3, pr[smi]))));
    }
  }
  float oc0 = 0.f, os0 = 0.f, oc1 = 0.f, os1 = 0.f;
#pragma unroll
  for (int smi = 0; smi < 16; ++smi) {
    const int sm = w * 16 + smi, sl = sm >> 3, m = sm & 7;
    float sv, cv;
    __sincosf(pr[smi], &sv, &cv);
    const float wt = Wm[sl * 8 + m];
    if (smi < 8) { oc0 = fmaf(wt, cv, oc0); os0 = fmaf(wt, sv, os0); }
    else         { oc1 = fmaf(wt, cv, oc1); os1 = fmaf(wt, sv, os1); }
  }
  const int sA = s0 + w * 2;
  const int bh = b * H_ + h;
  if (!kswz) {
    size_t e0 = ((size_t)bh * S_ + sA) * 128 + lane;
    unsigned short hh, ll;
    bsplit(oc0 * 0.125f, hh, ll); ((unsigned short*)oh)[e0] = hh;       ((unsigned short*)ol)[e0] = ll;
    bsplit(os0 * 0.125f, hh, ll); ((unsigned short*)oh)[e0 + 64] = hh;  ((unsigned short*)ol)[e0 + 64] = ll;
    bsplit(oc1 * 0.125f, hh, ll); ((unsigned short*)oh)[e0 + 128] = hh; ((unsigned short*)ol)[e0 + 128] = ll;
    bsplit(os1 * 0.125f, hh, ll); ((unsigned short*)oh)[e0 + 192] = hh; ((unsigned short*)ol)[e0 + 192] = ll;
  } else {
    auto put = [&](int s, int f, float v) {
      const int ch = s >> 5, klr = s & 31;
      const unsigned inner = (unsigned)(((klr << 8) + (f << 1)) ^ ((klr & 7) << 4));
      const size_t off = (size_t)bh * 262144 + (size_t)ch * 8192 + inner;
      unsigned short hh, ll; bsplit(v, hh, ll);
      *(unsigned short*)(oh + off) = hh;
      *(unsigned short*)(ol + off) = ll;
    };
    put(sA,     lane,      oc0 * 0.125f);
    put(sA,     64 + lane, os0 * 0.125f);
    put(sA + 1, lane,      oc1 * 0.125f);
    put(sA + 1, 64 + lane, os1 * 0.125f);
  }
}

// ---------------------------------------------------------------------------
// V projection fused with split/transpose/swizzle write.
// ---------------------------------------------------------------------------
__global__ __launch_bounds__(256) void k_proj_v(
    const float* __restrict__ atoms, const float* __restrict__ W,
    char* __restrict__ vthi, char* __restrict__ vtlo)
{
  const int s0 = blockIdx.x * 8;
  const int h  = blockIdx.y;
  const int b  = blockIdx.z;
  const int tid = threadIdx.x;
  const int w = tid >> 6, lane = tid & 63;

  __shared__ __align__(16) float Wt[64 * 65];
  __shared__ __align__(16) float As[8 * 8 * 64];
  __shared__ __align__(16) float T[8 * 517];

  for (int i = tid; i < 4096; i += 256) {
    const int dd = i >> 6, d = i & 63;
    Wt[d * 65 + dd] = W[h * 4096 + i];
  }
  for (int i = tid; i < 4096; i += 256)
    As[i] = atoms[(size_t)(b * S_ + s0) * 512 + i];
  __syncthreads();

  float acc[16];
#pragma unroll
  for (int i = 0; i < 16; ++i) acc[i] = 0.f;
#pragma unroll
  for (int d4 = 0; d4 < 16; ++d4) {
    const float w0 = Wt[(4 * d4 + 0) * 65 + lane];
    const float w1 = Wt[(4 * d4 + 1) * 65 + lane];
    const float w2 = Wt[(4 * d4 + 2) * 65 + lane];
    const float w3 = Wt[(4 * d4 + 3) * 65 + lane];
#pragma unroll
    for (int smi = 0; smi < 16; ++smi) {
      const float4 a = *(const float4*)&As[(w * 16 + smi) * 64 + 4 * d4];
      acc[smi] = fmaf(a.x, w0, fmaf(a.y, w1, fmaf(a.z, w2, fmaf(a.w, w3, acc[smi]))));
    }
  }
#pragma unroll
  for (int smi = 0; smi < 16; ++smi)
    T[(w * 2 + (smi >> 3)) * 517 + (smi & 7) * 64 + lane] = acc[smi];
  __syncthreads();

  const int bh = b * H_ + h;
  const int ch = s0 >> 5, half = (s0 >> 4) & 1, part2 = (s0 >> 3) & 1;
  const size_t base = (size_t)bh * 1048576 + (size_t)ch * 32768 + half * 16384;
#pragma unroll
  for (int j = 0; j < 2; ++j) {
    const int c = tid + j * 256;
    float v[8];
#pragma unroll
    for (int s = 0; s < 8; ++s) v[s] = T[s * 517 + c];
    unsigned hw[4], lw[4];
#pragma unroll
    for (int p = 0; p < 4; ++p) {
      const float a = v[2 * p], bb = v[2 * p + 1];
      const unsigned hword = cvt_pk_bf16(a, bb);
      const float ra = a - __uint_as_float(hword << 16);
      const float rb = bb - __uint_as_float(hword & 0xffff0000u);
      hw[p] = hword;
      lw[p] = cvt_pk_bf16(ra, rb);
    }
    const unsigned inner = (unsigned)((c * 32 + part2 * 16) ^ (((c >> 2) & 7) << 4));
    *(uint4*)(vthi + base + inner) = make_uint4(hw[0], hw[1], hw[2], hw[3]);
    *(uint4*)(vtlo + base + inner) = make_uint4(lw[0], lw[1], lw[2], lw[3]);
  }
}

// ---------------------------------------------------------------------------
// MFMA flash attention. Block = (bh, 32 q rows). Grid 512 -> 2 blocks/CU.
// 4 waves; each wave computes the full 32x32 score tile (redundant) and owns
// PV columns w*128 .. w*128+127 (4 accumulator frags = 64 AGPR).
// Chunk = 32 k; V staged in 16-k half-chunks (LDS 48KB).
// ---------------------------------------------------------------------------
__global__ __launch_bounds__(256, 2) void k_flash(
    const unsigned short* __restrict__ qrh, const unsigned short* __restrict__ qrl,
    const char* __restrict__ krh, const char* __restrict__ krl,
    const char* __restrict__ vthi, const char* __restrict__ vtlo,
    float* __restrict__ ao)
{
  extern __shared__ char sm[];
  char* Vhi = sm;                 // 16KB (one half-chunk, hi)
  char* Vlo = sm + 16384;         // 16KB
  char* Khi = sm + 32768;         // 8KB
  char* Klo = sm + 40960;         // 8KB

  const int tid = threadIdx.x;
  const int w = tid >> 6, lane = tid & 63;
  const int lrow = lane & 31, lhi = lane >> 5;

  const int phys = blockIdx.x;
  const int bh = ((phys & 7) << 1) | ((phys >> 3) & 1);  // XCD-local bh
  const int qb = phys >> 4;                              // 0..31
  const int b = bh >> 3, h = bh & 7;
  const int qbase = qb * 32;

  // Q fragments in registers (same 32 q rows for all 4 waves)
  uint4 qfh[8], qfl[8];
  {
    const size_t rowb = ((size_t)bh * S_ + qbase + lrow) * 128;
#pragma unroll
    for (int fs = 0; fs < 8; ++fs) {
      const size_t e = rowb + fs * 16 + lhi * 8;
      qfh[fs] = *(const uint4*)(qrh + e);
      qfl[fs] = *(const uint4*)(qrl + e);
    }
  }

  const char* vh_c = vthi + (size_t)bh * 1048576;
  const char* vl_c = vtlo + (size_t)bh * 1048576;
  const char* kh_c = krh + (size_t)bh * 262144;
  const char* kl_c = krl + (size_t)bh * 262144;

  auto issue_v = [&](int ch, int half) {
    const size_t g = (size_t)ch * 32768 + half * 16384;
#pragma unroll
    for (int i = 0; i < 4; ++i) {
      __builtin_amdgcn_global_load_lds(vh_c + g + i * 4096 + tid * 16, Vhi + i * 4096 + w * 1024, 16, 0, 0);
      __builtin_amdgcn_global_load_lds(vl_c + g + i * 4096 + tid * 16, Vlo + i * 4096 + w * 1024, 16, 0, 0);
    }
  };
  auto issue_k = [&](int ch) {
    const size_t g = (size_t)ch * 8192;
#pragma unroll
    for (int i = 0; i < 2; ++i) {
      __builtin_amdgcn_global_load_lds(kh_c + g + i * 4096 + tid * 16, Khi + i * 4096 + w * 1024, 16, 0, 0);
      __builtin_amdgcn_global_load_lds(kl_c + g + i * 4096 + tid * 16, Klo + i * 4096 + w * 1024, 16, 0, 0);
    }
  };

  f32x16 acc[4];
#pragma unroll
  for (int i = 0; i < 4; ++i)
#pragma unroll
    for (int r = 0; r < 16; ++r) acc[i][r] = 0.f;
  float m_run = -1e30f, l_run = 0.f;

  issue_v(0, 0);
  issue_k(0);

  for (int ch = 0; ch < 32; ++ch) {
    __syncthreads();   // Vhalf0(ch) + K(ch) ready

    // ---- scores: S[32k x 32q] (redundant across waves) ----
    f32x16 s;
#pragma unroll
    for (int r = 0; r < 16; ++r) s[r] = 0.f;
    __builtin_amdgcn_s_setprio(1);
#pragma unroll
    for (int fs = 0; fs < 8; ++fs) {
      const unsigned kaddr = (unsigned)((lrow * 256 + fs * 32 + lhi * 16) ^ ((lrow & 7) << 4));
      U4B8 kh, kl2, qh, ql;
      kh.u  = *(const uint4*)(Khi + kaddr);
      kl2.u = *(const uint4*)(Klo + kaddr);
      qh.u = qfh[fs]; ql.u = qfl[fs];
      s = __builtin_amdgcn_mfma_f32_32x32x16_bf16(kh.v,  qh.v, s, 0, 0, 0);
      s = __builtin_amdgcn_mfma_f32_32x32x16_bf16(kl2.v, qh.v, s, 0, 0, 0);
      s = __builtin_amdgcn_mfma_f32_32x32x16_bf16(kh.v,  ql.v, s, 0, 0, 0);
    }
    __builtin_amdgcn_s_setprio(0);

    // ---- online softmax (per q = lrow), defer-max ----
    float mx = s[0];
#pragma unroll
    for (int r = 1; r < 16; ++r) mx = fmaxf(mx, s[r]);
    mx = fmaxf(mx, __shfl_xor(mx, 32));
    if (!__all(mx <= m_run + 8.f)) {
      const float mnew = fmaxf(m_run, mx);
      const float sc = __expf(m_run - mnew);
      float scr[16];
#pragma unroll
      for (int r = 0; r < 16; ++r)
        scr[r] = __shfl(sc, (r & 3) + 8 * (r >> 2) + 4 * lhi);
#pragma unroll
      for (int i = 0; i < 4; ++i)
#pragma unroll
        for (int r = 0; r < 16; ++r) acc[i][r] *= scr[r];
      l_run *= sc;
      m_run = mnew;
    }
    float p[16];
#pragma unroll
    for (int r = 0; r < 16; ++r) p[r] = __expf(s[r] - m_run);
    float rs = 0.f;
#pragma unroll
    for (int r = 0; r < 16; ++r) rs += p[r];
    rs += __shfl_xor(rs, 32);
    l_run += rs;

    // ---- repack P (hi & lo splits) to PV A-fragments ----
    unsigned wh[8], wl[8];
#pragma unroll
    for (int i = 0; i < 8; ++i) {
      const float a = p[2 * i], c2 = p[2 * i + 1];
      const unsigned hword = cvt_pk_bf16(a, c2);
      const float ra = a - __uint_as_float(hword << 16);
      const float rc = c2 - __uint_as_float(hword & 0xffff0000u);
      wh[i] = hword;
      wl[i] = cvt_pk_bf16(ra, rc);
    }
    auto mix = [&](unsigned &lo_w, unsigned &hi_w) {
      const unsigned s_lo = (unsigned)__shfl_xor((int)lo_w, 32);
      const unsigned s_hi = (unsigned)__shfl_xor((int)hi_w, 32);
      const unsigned wlo = lhi ? s_hi : lo_w;
      const unsigned whi = lhi ? hi_w : s_lo;
      lo_w = wlo; hi_w = whi;
    };
    mix(wh[0], wh[2]); mix(wh[1], wh[3]); mix(wh[4], wh[6]); mix(wh[5], wh[7]);
    mix(wl[0], wl[2]); mix(wl[1], wl[3]); mix(wl[4], wl[6]); mix(wl[5], wl[7]);
    U4B8 pah0, pah1, pal0, pal1;
    pah0.u = make_uint4(wh[0], wh[1], wh[2], wh[3]);
    pah1.u = make_uint4(wh[4], wh[5], wh[6], wh[7]);
    pal0.u = make_uint4(wl[0], wl[1], wl[2], wl[3]);
    pal1.u = make_uint4(wl[4], wl[5], wl[6], wl[7]);

    // ---- PV half 0 (k 0..15 of chunk) ----
    __builtin_amdgcn_s_setprio(1);
#pragma unroll
    for (int cf = 0; cf < 4; ++cf) {
      const int c = w * 128 + cf * 32 + lrow;
      const unsigned vaddr = (unsigned)((c * 32 + lhi * 16) ^ (((c >> 2) & 7) << 4));
      U4B8 vh, vl2;
      vh.u  = *(const uint4*)(Vhi + vaddr);
      vl2.u = *(const uint4*)(Vlo + vaddr);
      acc[cf] = __builtin_amdgcn_mfma_f32_32x32x16_bf16(pah0.v, vh.v,  acc[cf], 0, 0, 0);
      acc[cf] = __builtin_amdgcn_mfma_f32_32x32x16_bf16(pal0.v, vh.v,  acc[cf], 0, 0, 0);
      acc[cf] = __builtin_amdgcn_mfma_f32_32x32x16_bf16(pah0.v, vl2.v, acc[cf], 0, 0, 0);
    }
    __builtin_amdgcn_s_setprio(0);
    __syncthreads();   // all reads of Vhalf0 + K(ch) done

    issue_v(ch, 1);
    if (ch < 31) issue_k(ch + 1);
    __syncthreads();   // Vhalf1 ready

    // ---- PV half 1 (k 16..31 of chunk) ----
    __builtin_amdgcn_s_setprio(1);
#pragma unroll
    for (int cf = 0; cf < 4; ++cf) {
      const int c = w * 128 + cf * 32 + lrow;
      const unsigned vaddr = (unsigned)((c * 32 + lhi * 16) ^ (((c >> 2) & 7) << 4));
      U4B8 vh, vl2;
      vh.u  = *(const uint4*)(Vhi + vaddr);
      vl2.u = *(const uint4*)(Vlo + vaddr);
      acc[cf] = __builtin_amdgcn_mfma_f32_32x32x16_bf16(pah1.v, vh.v,  acc[cf], 0, 0, 0);
      acc[cf] = __builtin_amdgcn_mfma_f32_32x32x16_bf16(pal1.v, vh.v,  acc[cf], 0, 0, 0);
      acc[cf] = __builtin_amdgcn_mfma_f32_32x32x16_bf16(pah1.v, vl2.v, acc[cf], 0, 0, 0);
    }
    __builtin_amdgcn_s_setprio(0);

    if (ch < 31) {
      __syncthreads();   // Vhalf1 reads done
      issue_v(ch + 1, 0);
    }
  }

  // ---- epilogue: normalize + store ----
  const float linv = 1.0f / l_run;
  float lr[16];
#pragma unroll
  for (int r = 0; r < 16; ++r)
    lr[r] = __shfl(linv, (r & 3) + 8 * (r >> 2) + 4 * lhi);
#pragma unroll
  for (int cf = 0; cf < 4; ++cf) {
    const int c = w * 128 + cf * 32 + lrow;
    const int m = c >> 6, dd = c & 63;
#pragma unroll
    for (int r = 0; r < 16; ++r) {
      const int qr = (r & 3) + 8 * (r >> 2) + 4 * lhi;
      const int srow = qbase + qr;
      const size_t off = (((size_t)(b * S_ + srow)) * 8 + m) * 512 + h * 64 + dd;
      ao[off] = acc[cf][r] * lr[r];
    }
  }
}

// ---------------------------------------------------------------------------
// out_atoms = ao @ Wo^T + fused log-weight delta (unchanged).
// ---------------------------------------------------------------------------
__global__ __launch_bounds__(256) void k_out(
    const float* __restrict__ ao, const float* __restrict__ Wo,
    const float* __restrict__ Ww, const float* __restrict__ qlw,
    float* __restrict__ out)
{
  const int s2 = blockIdx.x;
  const int b = blockIdx.z;
  const int s0 = s2 * 2;
  const int tid = threadIdx.x, w = tid >> 6, lane = tid & 63;

  __shared__ __align__(16) float As[16 * 512];
  __shared__ __align__(16) float WoS[64 * 65];
  __shared__ float Os[16 * 64];

  const float* abase = ao + (size_t)((b * S_ + s0) * 8) * 512;
#pragma unroll
  for (int j = 0; j < 8; ++j) {
    const int i = tid + 256 * j;
    *(float4*)&As[4 * i] = *(const float4*)&abase[4 * i];
  }
  float acc[4] = {0.f, 0.f, 0.f, 0.f};
  for (int ft = 0; ft < 8; ++ft) {
    __syncthreads();
    for (int i = tid; i < 4096; i += 256) {
      const int dwo = i >> 6, fi = i & 63;
      WoS[fi * 65 + dwo] = Wo[dwo * 512 + ft * 64 + fi];
    }
    __syncthreads();
#pragma unroll 8
    for (int fi = 0; fi < 64; ++fi) {
      const float wv = WoS[fi * 65 + lane];
      const int f = ft * 64 + fi;
#pragma unroll
      for (int ri = 0; ri < 4; ++ri)
        acc[ri] = fmaf(As[(w * 4 + ri) * 512 + f], wv, acc[ri]);
    }
  }
#pragma unroll
  for (int ri = 0; ri < 4; ++ri) {
    const int row = w * 4 + ri;
    const int R = (b * S_ + s0) * 8 + row;
    out[(size_t)R * 64 + lane] = acc[ri];
    Os[row * 64 + lane] = acc[ri];
  }
  __syncthreads();
  if (w < 2) {
    float mean = 0.f;
#pragma unroll
    for (int m = 0; m < 8; ++m) mean += Os[(w * 8 + m) * 64 + lane];
    mean *= 0.125f;
    float dsel = 0.f;
#pragma unroll
    for (int mw = 0; mw < 8; ++mw) {
      float part = mean * Ww[mw * 64 + lane];
      part += __shfl_xor(part, 1);
      part += __shfl_xor(part, 2);
      part += __shfl_xor(part, 4);
      part += __shfl_xor(part, 8);
      part += __shfl_xor(part, 16);
      part += __shfl_xor(part, 32);
      if (lane == mw) dsel = part;
    }
    if (lane < 8) {
      const int idx = (b * S_ + s0 + w) * 8 + lane;
      out[1048576 + idx] = qlw[idx] + dsel;
    }
  }
}

// ---------------------------------------------------------------------------
extern "C" void kernel_launch(void* const* d_in, const int* in_sizes, int n_in,
                              void* d_out, int out_size, void* d_ws, size_t ws_size,
                              hipStream_t stream)
{
  const float* q_atoms = (const float*)d_in[0];
  const float* q_logw  = (const float*)d_in[1];
  const float* k_atoms = (const float*)d_in[2];
  const float* k_logw  = (const float*)d_in[3];
  const float* v_atoms = (const float*)d_in[4];
  const float* cosT  = (const float*)d_in[6];
  const float* sinT  = (const float*)d_in[7];
  const float* Wq    = (const float*)d_in[8];
  const float* Wk    = (const float*)d_in[9];
  const float* Wv    = (const float*)d_in[10];
  const float* Wo    = (const float*)d_in[11];
  const float* Ww    = (const float*)d_in[12];
  const float* logbw = (const float*)d_in[13];
  const float* rffb  = (const float*)d_in[14];
  float* out = (float*)d_out;

  char* wsb = (char*)d_ws;
  char* qrh = wsb;
  char* qrl = wsb + (4u << 20);
  char* krh = wsb + (8u << 20);
  char* krl = wsb + (12u << 20);
  char* vthi = wsb + (16u << 20);
  char* vtlo = wsb + (32u << 20);
  float* ao = (float*)(wsb + (48u << 20));

  const dim3 blk(256);
  k_proj_rff<<<dim3(128, 8, 2), blk, 0, stream>>>(q_atoms, q_logw, Wq, rffb, logbw, cosT, sinT, qrh, qrl, 0);
  k_proj_rff<<<dim3(128, 8, 2), blk, 0, stream>>>(k_atoms, k_logw, Wk, rffb, logbw, cosT, sinT, krh, krl, 1);
  k_proj_v  <<<dim3(128, 8, 2), blk, 0, stream>>>(v_atoms, Wv, vthi, vtlo);
  k_flash   <<<dim3(512), blk, 49152, stream>>>((const unsigned short*)qrh, (const unsigned short*)qrl,
                                                krh, krl, vthi, vtlo, ao);
  k_out     <<<dim3(512, 1, 2), blk, 0, stream>>>(ao, Wo, Ww, q_logw, out);
}

// Round 5
// 319.820 us; speedup vs baseline: 3.0538x; 1.0020x over previous
//
#include <hip/hip_runtime.h>
#include <math.h>

// KME attention. B=2 S=1024 M=8 D=64 H=8 NF=64
// Round 5: k_flash -> 256 blocks x 512 threads (64q x 512c per block, 8 waves
// of 32q x 128c), raw s_barrier + counted vmcnt pipeline (loads in flight
// across barriers), K dbuf + V half-chunk buffers, LDS 96KB.
//
// ws layout (bytes), 80 MiB total:
//   qrh  @ 0MB   4MB  ushort [bh][s][128]          (natural)
//   qrl  @ 4MB   4MB
//   krh  @ 8MB   4MB  swizzled-chunk layout [bh][ch=32][8192B]
//   krl  @12MB   4MB
//   vthi @16MB  16MB  [bh][ch=32][half=2][16KB], inner=(c*32+p2*16)^(((c>>2)&7)<<4)
//   vtlo @32MB  16MB
//   ao   @48MB  32MB  f32 [b][s][m][512]

#define B_ 2
#define S_ 1024
#define H_ 8

typedef __attribute__((ext_vector_type(8))) short short8;
typedef __attribute__((ext_vector_type(16))) float f32x16;
union U4B8 { uint4 u; short8 v; };

#define SBAR() __builtin_amdgcn_s_barrier()
#define SCHED0() __builtin_amdgcn_sched_barrier(0)

__device__ inline unsigned cvt_pk_bf16(float a, float b) {
  unsigned r;
  asm("v_cvt_pk_bf16_f32 %0, %1, %2" : "=v"(r) : "v"(a), "v"(b));
  return r;
}
__device__ inline void bsplit(float v, unsigned short &h, unsigned short &l) {
  unsigned hw = cvt_pk_bf16(v, 0.f);
  float hf = __uint_as_float(hw << 16);
  unsigned lw = cvt_pk_bf16(v - hf, 0.f);
  h = (unsigned short)hw; l = (unsigned short)lw;
}

// ---------------------------------------------------------------------------
// Fused projection + RoPE + RFF encode (+ softmax-weighted sum over m).
// ---------------------------------------------------------------------------
__global__ __launch_bounds__(256) void k_proj_rff(
    const float* __restrict__ atoms, const float* __restrict__ logw,
    const float* __restrict__ W, const float* __restrict__ freqb,
    const float* __restrict__ logbw, const float* __restrict__ cosT,
    const float* __restrict__ sinT, char* __restrict__ oh,
    char* __restrict__ ol, int kswz)
{
  const int s0 = blockIdx.x * 8;
  const int h  = blockIdx.y;
  const int b  = blockIdx.z;
  const int tid = threadIdx.x;
  const int w = tid >> 6, lane = tid & 63;

  __shared__ __align__(16) float Wt[64 * 65];
  __shared__ __align__(16) float Fq[64 * 64];
  __shared__ __align__(16) float As[8 * 8 * 64];
  __shared__ __align__(16) float Qa[64 * 64];
  __shared__ __align__(16) float Cs[8 * 64];
  __shared__ __align__(16) float Sn[8 * 64];
  __shared__ float Wm[8 * 8];

  const float fscale = __expf(-logbw[h]);
  for (int i = tid; i < 4096; i += 256) {
    const int dd = i >> 6, d = i & 63;
    Wt[d * 65 + dd] = W[h * 4096 + i];
    Fq[i] = freqb[h * 4096 + i] * fscale;
  }
  for (int i = tid; i < 4096; i += 256)
    As[i] = atoms[(size_t)(b * S_ + s0) * 512 + i];
  for (int i = tid; i < 512; i += 256) {
    const int sl = i >> 6, d = i & 63;
    Cs[i] = cosT[(s0 + sl) * 64 + d];
    Sn[i] = sinT[(s0 + sl) * 64 + d];
  }
  if (tid < 8) {
    const float* lw = logw + (size_t)(b * S_ + s0 + tid) * 8;
    float mx = lw[0];
    for (int m = 1; m < 8; ++m) mx = fmaxf(mx, lw[m]);
    float e[8], sum = 0.f;
    for (int m = 0; m < 8; ++m) { e[m] = __expf(lw[m] - mx); sum += e[m]; }
    const float inv = 1.0f / sum;
    for (int m = 0; m < 8; ++m) Wm[tid * 8 + m] = e[m] * inv;
  }
  __syncthreads();

  float acc[16];
#pragma unroll
  for (int i = 0; i < 16; ++i) acc[i] = 0.f;
#pragma unroll
  for (int d4 = 0; d4 < 16; ++d4) {
    const float w0 = Wt[(4 * d4 + 0) * 65 + lane];
    const float w1 = Wt[(4 * d4 + 1) * 65 + lane];
    const float w2 = Wt[(4 * d4 + 2) * 65 + lane];
    const float w3 = Wt[(4 * d4 + 3) * 65 + lane];
#pragma unroll
    for (int smi = 0; smi < 16; ++smi) {
      const float4 a = *(const float4*)&As[(w * 16 + smi) * 64 + 4 * d4];
      acc[smi] = fmaf(a.x, w0, fmaf(a.y, w1, fmaf(a.z, w2, fmaf(a.w, w3, acc[smi]))));
    }
  }
#pragma unroll
  for (int smi = 0; smi < 16; ++smi) {
    const int sm = w * 16 + smi, sl = sm >> 3;
    const float other = __shfl_xor(acc[smi], 32);
    const float rot = (lane < 32) ? -other : other;
    Qa[sm * 64 + lane] = acc[smi] * Cs[sl * 64 + lane] + rot * Sn[sl * 64 + lane];
  }

  float pr[16];
#pragma unroll
  for (int i = 0; i < 16; ++i) pr[i] = 0.f;
#pragma unroll
  for (int d4 = 0; d4 < 16; ++d4) {
    const float f0 = Fq[(4 * d4 + 0) * 64 + lane];
    const float f1 = Fq[(4 * d4 + 1) * 64 + lane];
    const float f2 = Fq[(4 * d4 + 2) * 64 + lane];
    const float f3 = Fq[(4 * d4 + 3) * 64 + lane];
#pragma unroll
    for (int smi = 0; smi < 16; ++smi) {
      const float4 a = *(const float4*)&Qa[(w * 16 + smi) * 64 + 4 * d4];
      pr[smi] = fmaf(a.x, f0, fmaf(a.y, f1, fmaf(a.z, f2, fmaf(a.w, f3, pr[smi]))));
    }
  }
  float oc0 = 0.f, os0 = 0.f, oc1 = 0.f, os1 = 0.f;
#pragma unroll
  for (int smi = 0; smi < 16; ++smi) {
    const int sm = w * 16 + smi, sl = sm >> 3, m = sm & 7;
    float sv, cv;
    __sincosf(pr[smi], &sv, &cv);
    const float wt = Wm[sl * 8 + m];
    if (smi < 8) { oc0 = fmaf(wt, cv, oc0); os0 = fmaf(wt, sv, os0); }
    else         { oc1 = fmaf(wt, cv, oc1); os1 = fmaf(wt, sv, os1); }
  }
  const int sA = s0 + w * 2;
  const int bh = b * H_ + h;
  if (!kswz) {
    size_t e0 = ((size_t)bh * S_ + sA) * 128 + lane;
    unsigned short hh, ll;
    bsplit(oc0 * 0.125f, hh, ll); ((unsigned short*)oh)[e0] = hh;       ((unsigned short*)ol)[e0] = ll;
    bsplit(os0 * 0.125f, hh, ll); ((unsigned short*)oh)[e0 + 64] = hh;  ((unsigned short*)ol)[e0 + 64] = ll;
    bsplit(oc1 * 0.125f, hh, ll); ((unsigned short*)oh)[e0 + 128] = hh; ((unsigned short*)ol)[e0 + 128] = ll;
    bsplit(os1 * 0.125f, hh, ll); ((unsigned short*)oh)[e0 + 192] = hh; ((unsigned short*)ol)[e0 + 192] = ll;
  } else {
    auto put = [&](int s, int f, float v) {
      const int ch = s >> 5, klr = s & 31;
      const unsigned inner = (unsigned)(((klr << 8) + (f << 1)) ^ ((klr & 7) << 4));
      const size_t off = (size_t)bh * 262144 + (size_t)ch * 8192 + inner;
      unsigned short hh, ll; bsplit(v, hh, ll);
      *(unsigned short*)(oh + off) = hh;
      *(unsigned short*)(ol + off) = ll;
    };
    put(sA,     lane,      oc0 * 0.125f);
    put(sA,     64 + lane, os0 * 0.125f);
    put(sA + 1, lane,      oc1 * 0.125f);
    put(sA + 1, 64 + lane, os1 * 0.125f);
  }
}

// ---------------------------------------------------------------------------
// V projection fused with split/transpose/swizzle write.
// ---------------------------------------------------------------------------
__global__ __launch_bounds__(256) void k_proj_v(
    const float* __restrict__ atoms, const float* __restrict__ W,
    char* __restrict__ vthi, char* __restrict__ vtlo)
{
  const int s0 = blockIdx.x * 8;
  const int h  = blockIdx.y;
  const int b  = blockIdx.z;
  const int tid = threadIdx.x;
  const int w = tid >> 6, lane = tid & 63;

  __shared__ __align__(16) float Wt[64 * 65];
  __shared__ __align__(16) float As[8 * 8 * 64];
  __shared__ __align__(16) float T[8 * 517];

  for (int i = tid; i < 4096; i += 256) {
    const int dd = i >> 6, d = i & 63;
    Wt[d * 65 + dd] = W[h * 4096 + i];
  }
  for (int i = tid; i < 4096; i += 256)
    As[i] = atoms[(size_t)(b * S_ + s0) * 512 + i];
  __syncthreads();

  float acc[16];
#pragma unroll
  for (int i = 0; i < 16; ++i) acc[i] = 0.f;
#pragma unroll
  for (int d4 = 0; d4 < 16; ++d4) {
    const float w0 = Wt[(4 * d4 + 0) * 65 + lane];
    const float w1 = Wt[(4 * d4 + 1) * 65 + lane];
    const float w2 = Wt[(4 * d4 + 2) * 65 + lane];
    const float w3 = Wt[(4 * d4 + 3) * 65 + lane];
#pragma unroll
    for (int smi = 0; smi < 16; ++smi) {
      const float4 a = *(const float4*)&As[(w * 16 + smi) * 64 + 4 * d4];
      acc[smi] = fmaf(a.x, w0, fmaf(a.y, w1, fmaf(a.z, w2, fmaf(a.w, w3, acc[smi]))));
    }
  }
#pragma unroll
  for (int smi = 0; smi < 16; ++smi)
    T[(w * 2 + (smi >> 3)) * 517 + (smi & 7) * 64 + lane] = acc[smi];
  __syncthreads();

  const int bh = b * H_ + h;
  const int ch = s0 >> 5, half = (s0 >> 4) & 1, part2 = (s0 >> 3) & 1;
  const size_t base = (size_t)bh * 1048576 + (size_t)ch * 32768 + half * 16384;
#pragma unroll
  for (int j = 0; j < 2; ++j) {
    const int c = tid + j * 256;
    float v[8];
#pragma unroll
    for (int s = 0; s < 8; ++s) v[s] = T[s * 517 + c];
    unsigned hw[4], lw[4];
#pragma unroll
    for (int p = 0; p < 4; ++p) {
      const float a = v[2 * p], bb = v[2 * p + 1];
      const unsigned hword = cvt_pk_bf16(a, bb);
      const float ra = a - __uint_as_float(hword << 16);
      const float rb = bb - __uint_as_float(hword & 0xffff0000u);
      hw[p] = hword;
      lw[p] = cvt_pk_bf16(ra, rb);
    }
    const unsigned inner = (unsigned)((c * 32 + part2 * 16) ^ (((c >> 2) & 7) << 4));
    *(uint4*)(vthi + base + inner) = make_uint4(hw[0], hw[1], hw[2], hw[3]);
    *(uint4*)(vtlo + base + inner) = make_uint4(lw[0], lw[1], lw[2], lw[3]);
  }
}

// ---------------------------------------------------------------------------
// MFMA flash attention, counted-vmcnt pipeline.
// Block = (bh, 64 q rows), 512 threads = 8 waves: qw = w>>2 (32q), cw = w&3
// (128c). Grid 256 = 1 block/CU, 2 waves/SIMD.
// LDS 96KB: V half A (hi+lo 32KB), V half B (32KB), K dbuf (2 x hi+lo 16KB).
// Raw s_barrier + counted vmcnt: staging loads stay in flight across
// barriers; steady-state waits are vmcnt(6)/vmcnt(4), never 0.
// ---------------------------------------------------------------------------
__global__ __launch_bounds__(512, 1) void k_flash(
    const unsigned short* __restrict__ qrh, const unsigned short* __restrict__ qrl,
    const char* __restrict__ krh, const char* __restrict__ krl,
    const char* __restrict__ vthi, const char* __restrict__ vtlo,
    float* __restrict__ ao)
{
  extern __shared__ char smem[];
  char* VhiA = smem;                  // 16KB  (k 0..15 of chunk, hi)
  char* VloA = smem + 16384;          // 16KB
  char* VhiB = smem + 32768;          // 16KB  (k 16..31, hi)
  char* VloB = smem + 49152;          // 16KB
  char* Khi0 = smem + 65536;          // 8KB
  char* Klo0 = smem + 73728;          // 8KB
  char* Khi1 = smem + 81920;          // 8KB
  char* Klo1 = smem + 90112;          // 8KB

  const int tid = threadIdx.x;
  const int w = tid >> 6, lane = tid & 63;
  const int lrow = lane & 31, lhi = lane >> 5;
  const int qw = w >> 2, cw = w & 3;

  const int phys = blockIdx.x;
  const int x = phys & 7, j = phys >> 3;
  const int bh = (x << 1) | (j >> 4);     // XCD x serves bh {2x, 2x+1}
  const int qb = j & 15;
  const int b = bh >> 3, h = bh & 7;
  const int qbase = qb * 64 + qw * 32;

  // Q fragments in registers
  uint4 qfh[8], qfl[8];
  {
    const size_t rowb = ((size_t)bh * S_ + qbase + lrow) * 128;
#pragma unroll
    for (int fs = 0; fs < 8; ++fs) {
      const size_t e = rowb + fs * 16 + lhi * 8;
      qfh[fs] = *(const uint4*)(qrh + e);
      qfl[fs] = *(const uint4*)(qrl + e);
    }
  }

  const char* vh_c = vthi + (size_t)bh * 1048576;
  const char* vl_c = vtlo + (size_t)bh * 1048576;
  const char* kh_c = krh + (size_t)bh * 262144;
  const char* kl_c = krl + (size_t)bh * 262144;

  // 512-thread staging: per plane 16KB = 2 issues, 8KB = 1 issue.
  auto issue_vhalf = [&](char* dh, char* dl, int ch, int half) {
    const size_t g = (size_t)ch * 32768 + (size_t)half * 16384;
#pragma unroll
    for (int i = 0; i < 2; ++i) {
      __builtin_amdgcn_global_load_lds(vh_c + g + i * 8192 + tid * 16, dh + i * 8192 + (w << 10), 16, 0, 0);
      __builtin_amdgcn_global_load_lds(vl_c + g + i * 8192 + tid * 16, dl + i * 8192 + (w << 10), 16, 0, 0);
    }
  };
  auto issue_k = [&](int ch, char* dh, char* dl) {
    const size_t g = (size_t)ch * 8192;
    __builtin_amdgcn_global_load_lds(kh_c + g + tid * 16, dh + (w << 10), 16, 0, 0);
    __builtin_amdgcn_global_load_lds(kl_c + g + tid * 16, dl + (w << 10), 16, 0, 0);
  };

  f32x16 acc[4];
#pragma unroll
  for (int i = 0; i < 4; ++i)
#pragma unroll
    for (int r = 0; r < 16; ++r) acc[i][r] = 0.f;
  float m_run = -1e30f, l_run = 0.f;

  // Prologue: VA(0)[4], K(0)[2], VB(0)[4]; wait all but VB(0).
  issue_vhalf(VhiA, VloA, 0, 0);
  issue_k(0, Khi0, Klo0);
  issue_vhalf(VhiB, VloB, 0, 1);
  asm volatile("s_waitcnt vmcnt(4)" ::: "memory");
  SCHED0(); SBAR(); SCHED0();

  for (int ch = 0; ch < 32; ++ch) {
    const char* kh = (ch & 1) ? Khi1 : Khi0;
    const char* kl = (ch & 1) ? Klo1 : Klo0;

    // ---- scores: S[32k x 32q] (x4 redundancy across cw) ----
    f32x16 s;
#pragma unroll
    for (int r = 0; r < 16; ++r) s[r] = 0.f;
    __builtin_amdgcn_s_setprio(1);
#pragma unroll
    for (int fs = 0; fs < 8; ++fs) {
      const unsigned kaddr = (unsigned)((lrow * 256 + fs * 32 + lhi * 16) ^ ((lrow & 7) << 4));
      U4B8 khf, klf, qh, ql;
      khf.u = *(const uint4*)(kh + kaddr);
      klf.u = *(const uint4*)(kl + kaddr);
      qh.u = qfh[fs]; ql.u = qfl[fs];
      s = __builtin_amdgcn_mfma_f32_32x32x16_bf16(khf.v, qh.v, s, 0, 0, 0);
      s = __builtin_amdgcn_mfma_f32_32x32x16_bf16(klf.v, qh.v, s, 0, 0, 0);
      s = __builtin_amdgcn_mfma_f32_32x32x16_bf16(khf.v, ql.v, s, 0, 0, 0);
    }
    __builtin_amdgcn_s_setprio(0);

    // ---- online softmax (per q = lrow), defer-max ----
    float mx = s[0];
#pragma unroll
    for (int r = 1; r < 16; ++r) mx = fmaxf(mx, s[r]);
    mx = fmaxf(mx, __shfl_xor(mx, 32));
    if (!__all(mx <= m_run + 8.f)) {
      const float mnew = fmaxf(m_run, mx);
      const float sc = __expf(m_run - mnew);
      float scr[16];
#pragma unroll
      for (int r = 0; r < 16; ++r)
        scr[r] = __shfl(sc, (r & 3) + 8 * (r >> 2) + 4 * lhi);
#pragma unroll
      for (int i = 0; i < 4; ++i)
#pragma unroll
        for (int r = 0; r < 16; ++r) acc[i][r] *= scr[r];
      l_run *= sc;
      m_run = mnew;
    }
    float p[16];
#pragma unroll
    for (int r = 0; r < 16; ++r) p[r] = __expf(s[r] - m_run);
    float rs = 0.f;
#pragma unroll
    for (int r = 0; r < 16; ++r) rs += p[r];
    rs += __shfl_xor(rs, 32);
    l_run += rs;

    // ---- repack P (hi & lo splits) to PV A-fragments ----
    unsigned wh[8], wl[8];
#pragma unroll
    for (int i = 0; i < 8; ++i) {
      const float a = p[2 * i], c2 = p[2 * i + 1];
      const unsigned hword = cvt_pk_bf16(a, c2);
      const float ra = a - __uint_as_float(hword << 16);
      const float rc = c2 - __uint_as_float(hword & 0xffff0000u);
      wh[i] = hword;
      wl[i] = cvt_pk_bf16(ra, rc);
    }
    auto mix = [&](unsigned &lo_w, unsigned &hi_w) {
      const unsigned s_lo = (unsigned)__shfl_xor((int)lo_w, 32);
      const unsigned s_hi = (unsigned)__shfl_xor((int)hi_w, 32);
      const unsigned wlo = lhi ? s_hi : lo_w;
      const unsigned whi = lhi ? hi_w : s_lo;
      lo_w = wlo; hi_w = whi;
    };
    mix(wh[0], wh[2]); mix(wh[1], wh[3]); mix(wh[4], wh[6]); mix(wh[5], wh[7]);
    mix(wl[0], wl[2]); mix(wl[1], wl[3]); mix(wl[4], wl[6]); mix(wl[5], wl[7]);
    U4B8 pah0, pah1, pal0, pal1;
    pah0.u = make_uint4(wh[0], wh[1], wh[2], wh[3]);
    pah1.u = make_uint4(wh[4], wh[5], wh[6], wh[7]);
    pal0.u = make_uint4(wl[0], wl[1], wl[2], wl[3]);
    pal1.u = make_uint4(wl[4], wl[5], wl[6], wl[7]);

    // ---- PV half A (k 0..15) ----
    __builtin_amdgcn_s_setprio(1);
#pragma unroll
    for (int cf = 0; cf < 4; ++cf) {
      const int c = cw * 128 + cf * 32 + lrow;
      const unsigned vaddr = (unsigned)((c * 32 + lhi * 16) ^ (((c >> 2) & 7) << 4));
      U4B8 vh, vl2;
      vh.u  = *(const uint4*)(VhiA + vaddr);
      vl2.u = *(const uint4*)(VloA + vaddr);
      acc[cf] = __builtin_amdgcn_mfma_f32_32x32x16_bf16(pah0.v, vh.v,  acc[cf], 0, 0, 0);
      acc[cf] = __builtin_amdgcn_mfma_f32_32x32x16_bf16(pal0.v, vh.v,  acc[cf], 0, 0, 0);
      acc[cf] = __builtin_amdgcn_mfma_f32_32x32x16_bf16(pah0.v, vl2.v, acc[cf], 0, 0, 0);
    }
    __builtin_amdgcn_s_setprio(0);

    SBAR(); SCHED0();                       // VA & K[ch] readers done
    if (ch < 31) {
      issue_vhalf(VhiA, VloA, ch + 1, 0);   // 4 loads
      issue_k(ch + 1, (ch & 1) ? Khi0 : Khi1, (ch & 1) ? Klo0 : Klo1);  // 2
      asm volatile("s_waitcnt vmcnt(6)" ::: "memory");   // VB(ch) ready
    } else {
      asm volatile("s_waitcnt vmcnt(0)" ::: "memory");
    }
    SCHED0(); SBAR(); SCHED0();

    // ---- PV half B (k 16..31) ----
    __builtin_amdgcn_s_setprio(1);
#pragma unroll
    for (int cf = 0; cf < 4; ++cf) {
      const int c = cw * 128 + cf * 32 + lrow;
      const unsigned vaddr = (unsigned)((c * 32 + lhi * 16) ^ (((c >> 2) & 7) << 4));
      U4B8 vh, vl2;
      vh.u  = *(const uint4*)(VhiB + vaddr);
      vl2.u = *(const uint4*)(VloB + vaddr);
      acc[cf] = __builtin_amdgcn_mfma_f32_32x32x16_bf16(pah1.v, vh.v,  acc[cf], 0, 0, 0);
      acc[cf] = __builtin_amdgcn_mfma_f32_32x32x16_bf16(pal1.v, vh.v,  acc[cf], 0, 0, 0);
      acc[cf] = __builtin_amdgcn_mfma_f32_32x32x16_bf16(pah1.v, vl2.v, acc[cf], 0, 0, 0);
    }
    __builtin_amdgcn_s_setprio(0);

    if (ch < 31) {
      SBAR(); SCHED0();                     // VB readers done
      issue_vhalf(VhiB, VloB, ch + 1, 1);   // 4 loads
      asm volatile("s_waitcnt vmcnt(4)" ::: "memory");   // VA(ch+1), K(ch+1) ready
      SCHED0(); SBAR(); SCHED0();
    }
  }

  // ---- epilogue: normalize + store ----
  const float linv = 1.0f / l_run;
  float lr[16];
#pragma unroll
  for (int r = 0; r < 16; ++r)
    lr[r] = __shfl(linv, (r & 3) + 8 * (r >> 2) + 4 * lhi);
#pragma unroll
  for (int cf = 0; cf < 4; ++cf) {
    const int c = cw * 128 + cf * 32 + lrow;
    const int m = c >> 6, dd = c & 63;
#pragma unroll
    for (int r = 0; r < 16; ++r) {
      const int qr = (r & 3) + 8 * (r >> 2) + 4 * lhi;
      const int srow = qbase + qr;
      const size_t off = (((size_t)(b * S_ + srow)) * 8 + m) * 512 + h * 64 + dd;
      ao[off] = acc[cf][r] * lr[r];
    }
  }
}

// ---------------------------------------------------------------------------
// out_atoms = ao @ Wo^T + fused log-weight delta (unchanged).
// ---------------------------------------------------------------------------
__global__ __launch_bounds__(256) void k_out(
    const float* __restrict__ ao, const float* __restrict__ Wo,
    const float* __restrict__ Ww, const float* __restrict__ qlw,
    float* __restrict__ out)
{
  const int s2 = blockIdx.x;
  const int b = blockIdx.z;
  const int s0 = s2 * 2;
  const int tid = threadIdx.x, w = tid >> 6, lane = tid & 63;

  __shared__ __align__(16) float As[16 * 512];
  __shared__ __align__(16) float WoS[64 * 65];
  __shared__ float Os[16 * 64];

  const float* abase = ao + (size_t)((b * S_ + s0) * 8) * 512;
#pragma unroll
  for (int j = 0; j < 8; ++j) {
    const int i = tid + 256 * j;
    *(float4*)&As[4 * i] = *(const float4*)&abase[4 * i];
  }
  float acc[4] = {0.f, 0.f, 0.f, 0.f};
  for (int ft = 0; ft < 8; ++ft) {
    __syncthreads();
    for (int i = tid; i < 4096; i += 256) {
      const int dwo = i >> 6, fi = i & 63;
      WoS[fi * 65 + dwo] = Wo[dwo * 512 + ft * 64 + fi];
    }
    __syncthreads();
#pragma unroll 8
    for (int fi = 0; fi < 64; ++fi) {
      const float wv = WoS[fi * 65 + lane];
      const int f = ft * 64 + fi;
#pragma unroll
      for (int ri = 0; ri < 4; ++ri)
        acc[ri] = fmaf(As[(w * 4 + ri) * 512 + f], wv, acc[ri]);
    }
  }
#pragma unroll
  for (int ri = 0; ri < 4; ++ri) {
    const int row = w * 4 + ri;
    const int R = (b * S_ + s0) * 8 + row;
    out[(size_t)R * 64 + lane] = acc[ri];
    Os[row * 64 + lane] = acc[ri];
  }
  __syncthreads();
  if (w < 2) {
    float mean = 0.f;
#pragma unroll
    for (int m = 0; m < 8; ++m) mean += Os[(w * 8 + m) * 64 + lane];
    mean *= 0.125f;
    float dsel = 0.f;
#pragma unroll
    for (int mw = 0; mw < 8; ++mw) {
      float part = mean * Ww[mw * 64 + lane];
      part += __shfl_xor(part, 1);
      part += __shfl_xor(part, 2);
      part += __shfl_xor(part, 4);
      part += __shfl_xor(part, 8);
      part += __shfl_xor(part, 16);
      part += __shfl_xor(part, 32);
      if (lane == mw) dsel = part;
    }
    if (lane < 8) {
      const int idx = (b * S_ + s0 + w) * 8 + lane;
      out[1048576 + idx] = qlw[idx] + dsel;
    }
  }
}

// ---------------------------------------------------------------------------
extern "C" void kernel_launch(void* const* d_in, const int* in_sizes, int n_in,
                              void* d_out, int out_size, void* d_ws, size_t ws_size,
                              hipStream_t stream)
{
  const float* q_atoms = (const float*)d_in[0];
  const float* q_logw  = (const float*)d_in[1];
  const float* k_atoms = (const float*)d_in[2];
  const float* k_logw  = (const float*)d_in[3];
  const float* v_atoms = (const float*)d_in[4];
  const float* cosT  = (const float*)d_in[6];
  const float* sinT  = (const float*)d_in[7];
  const float* Wq    = (const float*)d_in[8];
  const float* Wk    = (const float*)d_in[9];
  const float* Wv    = (const float*)d_in[10];
  const float* Wo    = (const float*)d_in[11];
  const float* Ww    = (const float*)d_in[12];
  const float* logbw = (const float*)d_in[13];
  const float* rffb  = (const float*)d_in[14];
  float* out = (float*)d_out;

  char* wsb = (char*)d_ws;
  char* qrh = wsb;
  char* qrl = wsb + (4u << 20);
  char* krh = wsb + (8u << 20);
  char* krl = wsb + (12u << 20);
  char* vthi = wsb + (16u << 20);
  char* vtlo = wsb + (32u << 20);
  float* ao = (float*)(wsb + (48u << 20));

  const dim3 blk(256);
  k_proj_rff<<<dim3(128, 8, 2), blk, 0, stream>>>(q_atoms, q_logw, Wq, rffb, logbw, cosT, sinT, qrh, qrl, 0);
  k_proj_rff<<<dim3(128, 8, 2), blk, 0, stream>>>(k_atoms, k_logw, Wk, rffb, logbw, cosT, sinT, krh, krl, 1);
  k_proj_v  <<<dim3(128, 8, 2), blk, 0, stream>>>(v_atoms, Wv, vthi, vtlo);
  k_flash   <<<dim3(256), dim3(512), 98304, stream>>>((const unsigned short*)qrh, (const unsigned short*)qrl,
                                                      krh, krl, vthi, vtlo, ao);
  k_out     <<<dim3(512, 1, 2), blk, 0, stream>>>(ao, Wo, Ww, q_logw, out);
}

// Round 6
// 310.810 us; speedup vs baseline: 3.1423x; 1.0290x over previous
//
#include <hip/hip_runtime.h>
#include <math.h>

// KME attention. B=2 S=1024 M=8 D=64 H=8 NF=64
// Round 6: k_flash reads V global->VGPR (reg double-buffer, no LDS staging);
// LDS holds only K dbuf (32KB). One vmcnt(16)+s_barrier per chunk for K DMA.
// Repack mix uses 1 shuffle. k_proj_v writes V unswizzled.
//
// ws layout (bytes), 80 MiB total:
//   qrh  @ 0MB   4MB  ushort [bh][s][128]          (natural)
//   qrl  @ 4MB   4MB
//   krh  @ 8MB   4MB  swizzled-chunk layout [bh][ch=32][8192B]
//   krl  @12MB   4MB
//   vthi @16MB  16MB  [bh][ch=32][half=2][c=512][32B], inner=c*32+part2*16
//   vtlo @32MB  16MB
//   ao   @48MB  32MB  f32 [b][s][m][512]

#define B_ 2
#define S_ 1024
#define H_ 8

typedef __attribute__((ext_vector_type(8))) short short8;
typedef __attribute__((ext_vector_type(16))) float f32x16;
union U4B8 { uint4 u; short8 v; };

#define SBAR() __builtin_amdgcn_s_barrier()
#define SCHED0() __builtin_amdgcn_sched_barrier(0)

__device__ inline unsigned cvt_pk_bf16(float a, float b) {
  unsigned r;
  asm("v_cvt_pk_bf16_f32 %0, %1, %2" : "=v"(r) : "v"(a), "v"(b));
  return r;
}
__device__ inline void bsplit(float v, unsigned short &h, unsigned short &l) {
  unsigned hw = cvt_pk_bf16(v, 0.f);
  float hf = __uint_as_float(hw << 16);
  unsigned lw = cvt_pk_bf16(v - hf, 0.f);
  h = (unsigned short)hw; l = (unsigned short)lw;
}

// ---------------------------------------------------------------------------
// Fused projection + RoPE + RFF encode (+ softmax-weighted sum over m).
// ---------------------------------------------------------------------------
__global__ __launch_bounds__(256) void k_proj_rff(
    const float* __restrict__ atoms, const float* __restrict__ logw,
    const float* __restrict__ W, const float* __restrict__ freqb,
    const float* __restrict__ logbw, const float* __restrict__ cosT,
    const float* __restrict__ sinT, char* __restrict__ oh,
    char* __restrict__ ol, int kswz)
{
  const int s0 = blockIdx.x * 8;
  const int h  = blockIdx.y;
  const int b  = blockIdx.z;
  const int tid = threadIdx.x;
  const int w = tid >> 6, lane = tid & 63;

  __shared__ __align__(16) float Wt[64 * 65];
  __shared__ __align__(16) float Fq[64 * 64];
  __shared__ __align__(16) float As[8 * 8 * 64];
  __shared__ __align__(16) float Qa[64 * 64];
  __shared__ __align__(16) float Cs[8 * 64];
  __shared__ __align__(16) float Sn[8 * 64];
  __shared__ float Wm[8 * 8];

  const float fscale = __expf(-logbw[h]);
  for (int i = tid; i < 4096; i += 256) {
    const int dd = i >> 6, d = i & 63;
    Wt[d * 65 + dd] = W[h * 4096 + i];
    Fq[i] = freqb[h * 4096 + i] * fscale;
  }
  for (int i = tid; i < 4096; i += 256)
    As[i] = atoms[(size_t)(b * S_ + s0) * 512 + i];
  for (int i = tid; i < 512; i += 256) {
    const int sl = i >> 6, d = i & 63;
    Cs[i] = cosT[(s0 + sl) * 64 + d];
    Sn[i] = sinT[(s0 + sl) * 64 + d];
  }
  if (tid < 8) {
    const float* lw = logw + (size_t)(b * S_ + s0 + tid) * 8;
    float mx = lw[0];
    for (int m = 1; m < 8; ++m) mx = fmaxf(mx, lw[m]);
    float e[8], sum = 0.f;
    for (int m = 0; m < 8; ++m) { e[m] = __expf(lw[m] - mx); sum += e[m]; }
    const float inv = 1.0f / sum;
    for (int m = 0; m < 8; ++m) Wm[tid * 8 + m] = e[m] * inv;
  }
  __syncthreads();

  float acc[16];
#pragma unroll
  for (int i = 0; i < 16; ++i) acc[i] = 0.f;
#pragma unroll
  for (int d4 = 0; d4 < 16; ++d4) {
    const float w0 = Wt[(4 * d4 + 0) * 65 + lane];
    const float w1 = Wt[(4 * d4 + 1) * 65 + lane];
    const float w2 = Wt[(4 * d4 + 2) * 65 + lane];
    const float w3 = Wt[(4 * d4 + 3) * 65 + lane];
#pragma unroll
    for (int smi = 0; smi < 16; ++smi) {
      const float4 a = *(const float4*)&As[(w * 16 + smi) * 64 + 4 * d4];
      acc[smi] = fmaf(a.x, w0, fmaf(a.y, w1, fmaf(a.z, w2, fmaf(a.w, w3, acc[smi]))));
    }
  }
#pragma unroll
  for (int smi = 0; smi < 16; ++smi) {
    const int sm = w * 16 + smi, sl = sm >> 3;
    const float other = __shfl_xor(acc[smi], 32);
    const float rot = (lane < 32) ? -other : other;
    Qa[sm * 64 + lane] = acc[smi] * Cs[sl * 64 + lane] + rot * Sn[sl * 64 + lane];
  }

  float pr[16];
#pragma unroll
  for (int i = 0; i < 16; ++i) pr[i] = 0.f;
#pragma unroll
  for (int d4 = 0; d4 < 16; ++d4) {
    const float f0 = Fq[(4 * d4 + 0) * 64 + lane];
    const float f1 = Fq[(4 * d4 + 1) * 64 + lane];
    const float f2 = Fq[(4 * d4 + 2) * 64 + lane];
    const float f3 = Fq[(4 * d4 + 3) * 64 + lane];
#pragma unroll
    for (int smi = 0; smi < 16; ++smi) {
      const float4 a = *(const float4*)&Qa[(w * 16 + smi) * 64 + 4 * d4];
      pr[smi] = fmaf(a.x, f0, fmaf(a.y, f1, fmaf(a.z, f2, fmaf(a.w, f3, pr[smi]))));
    }
  }
  float oc0 = 0.f, os0 = 0.f, oc1 = 0.f, os1 = 0.f;
#pragma unroll
  for (int smi = 0; smi < 16; ++smi) {
    const int sm = w * 16 + smi, sl = sm >> 3, m = sm & 7;
    float sv, cv;
    __sincosf(pr[smi], &sv, &cv);
    const float wt = Wm[sl * 8 + m];
    if (smi < 8) { oc0 = fmaf(wt, cv, oc0); os0 = fmaf(wt, sv, os0); }
    else         { oc1 = fmaf(wt, cv, oc1); os1 = fmaf(wt, sv, os1); }
  }
  const int sA = s0 + w * 2;
  const int bh = b * H_ + h;
  if (!kswz) {
    size_t e0 = ((size_t)bh * S_ + sA) * 128 + lane;
    unsigned short hh, ll;
    bsplit(oc0 * 0.125f, hh, ll); ((unsigned short*)oh)[e0] = hh;       ((unsigned short*)ol)[e0] = ll;
    bsplit(os0 * 0.125f, hh, ll); ((unsigned short*)oh)[e0 + 64] = hh;  ((unsigned short*)ol)[e0 + 64] = ll;
    bsplit(oc1 * 0.125f, hh, ll); ((unsigned short*)oh)[e0 + 128] = hh; ((unsigned short*)ol)[e0 + 128] = ll;
    bsplit(os1 * 0.125f, hh, ll); ((unsigned short*)oh)[e0 + 192] = hh; ((unsigned short*)ol)[e0 + 192] = ll;
  } else {
    auto put = [&](int s, int f, float v) {
      const int ch = s >> 5, klr = s & 31;
      const unsigned inner = (unsigned)(((klr << 8) + (f << 1)) ^ ((klr & 7) << 4));
      const size_t off = (size_t)bh * 262144 + (size_t)ch * 8192 + inner;
      unsigned short hh, ll; bsplit(v, hh, ll);
      *(unsigned short*)(oh + off) = hh;
      *(unsigned short*)(ol + off) = ll;
    };
    put(sA,     lane,      oc0 * 0.125f);
    put(sA,     64 + lane, os0 * 0.125f);
    put(sA + 1, lane,      oc1 * 0.125f);
    put(sA + 1, 64 + lane, os1 * 0.125f);
  }
}

// ---------------------------------------------------------------------------
// V projection fused with split/transpose write (UNSWIZZLED: k_flash reads
// V from global now, so no bank-swizzle needed).
// ---------------------------------------------------------------------------
__global__ __launch_bounds__(256) void k_proj_v(
    const float* __restrict__ atoms, const float* __restrict__ W,
    char* __restrict__ vthi, char* __restrict__ vtlo)
{
  const int s0 = blockIdx.x * 8;
  const int h  = blockIdx.y;
  const int b  = blockIdx.z;
  const int tid = threadIdx.x;
  const int w = tid >> 6, lane = tid & 63;

  __shared__ __align__(16) float Wt[64 * 65];
  __shared__ __align__(16) float As[8 * 8 * 64];
  __shared__ __align__(16) float T[8 * 517];

  for (int i = tid; i < 4096; i += 256) {
    const int dd = i >> 6, d = i & 63;
    Wt[d * 65 + dd] = W[h * 4096 + i];
  }
  for (int i = tid; i < 4096; i += 256)
    As[i] = atoms[(size_t)(b * S_ + s0) * 512 + i];
  __syncthreads();

  float acc[16];
#pragma unroll
  for (int i = 0; i < 16; ++i) acc[i] = 0.f;
#pragma unroll
  for (int d4 = 0; d4 < 16; ++d4) {
    const float w0 = Wt[(4 * d4 + 0) * 65 + lane];
    const float w1 = Wt[(4 * d4 + 1) * 65 + lane];
    const float w2 = Wt[(4 * d4 + 2) * 65 + lane];
    const float w3 = Wt[(4 * d4 + 3) * 65 + lane];
#pragma unroll
    for (int smi = 0; smi < 16; ++smi) {
      const float4 a = *(const float4*)&As[(w * 16 + smi) * 64 + 4 * d4];
      acc[smi] = fmaf(a.x, w0, fmaf(a.y, w1, fmaf(a.z, w2, fmaf(a.w, w3, acc[smi]))));
    }
  }
#pragma unroll
  for (int smi = 0; smi < 16; ++smi)
    T[(w * 2 + (smi >> 3)) * 517 + (smi & 7) * 64 + lane] = acc[smi];
  __syncthreads();

  const int bh = b * H_ + h;
  const int ch = s0 >> 5, half = (s0 >> 4) & 1, part2 = (s0 >> 3) & 1;
  const size_t base = (size_t)bh * 1048576 + (size_t)ch * 32768 + half * 16384;
#pragma unroll
  for (int j = 0; j < 2; ++j) {
    const int c = tid + j * 256;
    float v[8];
#pragma unroll
    for (int s = 0; s < 8; ++s) v[s] = T[s * 517 + c];
    unsigned hw[4], lw[4];
#pragma unroll
    for (int p = 0; p < 4; ++p) {
      const float a = v[2 * p], bb = v[2 * p + 1];
      const unsigned hword = cvt_pk_bf16(a, bb);
      const float ra = a - __uint_as_float(hword << 16);
      const float rb = bb - __uint_as_float(hword & 0xffff0000u);
      hw[p] = hword;
      lw[p] = cvt_pk_bf16(ra, rb);
    }
    const unsigned inner = (unsigned)(c * 32 + part2 * 16);
    *(uint4*)(vthi + base + inner) = make_uint4(hw[0], hw[1], hw[2], hw[3]);
    *(uint4*)(vtlo + base + inner) = make_uint4(lw[0], lw[1], lw[2], lw[3]);
  }
}

// ---------------------------------------------------------------------------
// MFMA flash attention. Block = (bh, 64 q rows), 512 threads = 8 waves:
// qw = w>>2 (32q), cw = w&3 (128c). Grid 256 = 1 block/CU.
// K through LDS (dbuf, 32KB static); V global->VGPR double-buffered regs
// (each wave's 128 columns are private -> no LDS staging needed).
// One vmcnt(16)+s_barrier per chunk for K DMA; V waits are compiler-managed.
// ---------------------------------------------------------------------------
__global__ __launch_bounds__(512, 1) void k_flash(
    const unsigned short* __restrict__ qrh, const unsigned short* __restrict__ qrl,
    const char* __restrict__ krh, const char* __restrict__ krl,
    const char* __restrict__ vthi, const char* __restrict__ vtlo,
    float* __restrict__ ao)
{
  __shared__ __align__(16) char smem[32768];
  char* Khi0 = smem;
  char* Klo0 = smem + 8192;
  char* Khi1 = smem + 16384;
  char* Klo1 = smem + 24576;

  const int tid = threadIdx.x;
  const int w = tid >> 6, lane = tid & 63;
  const int lrow = lane & 31, lhi = lane >> 5;
  const int cw = w & 3;

  const int phys = blockIdx.x;
  const int x = phys & 7, j = phys >> 3;
  const int bh = (x << 1) | (j >> 4);     // XCD x serves bh {2x, 2x+1}
  const int qb = j & 15;
  const int b = bh >> 3, h = bh & 7;
  const int qbase = qb * 64 + (w >> 2) * 32;

  // Q fragments in registers
  uint4 qfh[8], qfl[8];
  {
    const size_t rowb = ((size_t)bh * S_ + qbase + lrow) * 128;
#pragma unroll
    for (int fs = 0; fs < 8; ++fs) {
      const size_t e = rowb + fs * 16 + lhi * 8;
      qfh[fs] = *(const uint4*)(qrh + e);
      qfl[fs] = *(const uint4*)(qrl + e);
    }
  }

  const char* vh_c = vthi + (size_t)bh * 1048576;
  const char* vl_c = vtlo + (size_t)bh * 1048576;
  const char* kh_c = krh + (size_t)bh * 262144;
  const char* kl_c = krl + (size_t)bh * 262144;

  auto issue_k = [&](int ch, char* dh, char* dl) {
    const size_t g = (size_t)ch * 8192;
    __builtin_amdgcn_global_load_lds(kh_c + g + tid * 16, dh + (w << 10), 16, 0, 0);
    __builtin_amdgcn_global_load_lds(kl_c + g + tid * 16, dl + (w << 10), 16, 0, 0);
  };

  // V register double-buffer: wave's column base (c = cw*128 + cf*32 + lrow)
  const unsigned vbase = (unsigned)((cw * 128 + lrow) * 32 + lhi * 16);
  uint4 vAh[4], vAl[4], vBh[4], vBl[4];
  auto load_vA = [&](int ch) {
    const size_t g = (size_t)ch * 32768 + vbase;
#pragma unroll
    for (int cf = 0; cf < 4; ++cf) {
      vAh[cf] = *(const uint4*)(vh_c + g + cf * 1024);
      vAl[cf] = *(const uint4*)(vl_c + g + cf * 1024);
    }
  };
  auto load_vB = [&](int ch) {
    const size_t g = (size_t)ch * 32768 + 16384 + vbase;
#pragma unroll
    for (int cf = 0; cf < 4; ++cf) {
      vBh[cf] = *(const uint4*)(vh_c + g + cf * 1024);
      vBl[cf] = *(const uint4*)(vl_c + g + cf * 1024);
    }
  };

  f32x16 acc[4];
#pragma unroll
  for (int i = 0; i < 4; ++i)
#pragma unroll
    for (int r = 0; r < 16; ++r) acc[i][r] = 0.f;
  float m_run = -1e30f, l_run = 0.f;

  // Prologue: pin K(0) DMA, then V(0) reg loads; vmcnt(16) drains qf+K.
  SCHED0();
  issue_k(0, Khi0, Klo0);
  SCHED0();
  load_vA(0);
  load_vB(0);
  asm volatile("s_waitcnt vmcnt(16)" ::: "memory");
  SBAR(); SCHED0();

  for (int ch = 0; ch < 32; ++ch) {
    const char* kh = (ch & 1) ? Khi1 : Khi0;
    const char* kl = (ch & 1) ? Klo1 : Klo0;

    // ---- scores: S[32k x 32q] ----
    f32x16 s;
#pragma unroll
    for (int r = 0; r < 16; ++r) s[r] = 0.f;
    __builtin_amdgcn_s_setprio(1);
#pragma unroll
    for (int fs = 0; fs < 8; ++fs) {
      const unsigned kaddr = (unsigned)((lrow * 256 + fs * 32 + lhi * 16) ^ ((lrow & 7) << 4));
      U4B8 khf, klf, qh, ql;
      khf.u = *(const uint4*)(kh + kaddr);
      klf.u = *(const uint4*)(kl + kaddr);
      qh.u = qfh[fs]; ql.u = qfl[fs];
      s = __builtin_amdgcn_mfma_f32_32x32x16_bf16(khf.v, qh.v, s, 0, 0, 0);
      s = __builtin_amdgcn_mfma_f32_32x32x16_bf16(klf.v, qh.v, s, 0, 0, 0);
      s = __builtin_amdgcn_mfma_f32_32x32x16_bf16(khf.v, ql.v, s, 0, 0, 0);
    }
    __builtin_amdgcn_s_setprio(0);

    // K(ch+1) DMA into the other buffer (pinned so it's oldest in vmcnt).
    if (ch < 31) {
      SCHED0();
      issue_k(ch + 1, (ch & 1) ? Khi0 : Khi1, (ch & 1) ? Klo0 : Klo1);
      SCHED0();
    }

    // ---- online softmax (per q = lrow), defer-max ----
    float mx = s[0];
#pragma unroll
    for (int r = 1; r < 16; ++r) mx = fmaxf(mx, s[r]);
    mx = fmaxf(mx, __shfl_xor(mx, 32));
    if (!__all(mx <= m_run + 8.f)) {
      const float mnew = fmaxf(m_run, mx);
      const float sc = __expf(m_run - mnew);
      float scr[16];
#pragma unroll
      for (int r = 0; r < 16; ++r)
        scr[r] = __shfl(sc, (r & 3) + 8 * (r >> 2) + 4 * lhi);
#pragma unroll
      for (int i = 0; i < 4; ++i)
#pragma unroll
        for (int r = 0; r < 16; ++r) acc[i][r] *= scr[r];
      l_run *= sc;
      m_run = mnew;
    }
    float p[16];
#pragma unroll
    for (int r = 0; r < 16; ++r) p[r] = __expf(s[r] - m_run);
    float rs = 0.f;
#pragma unroll
    for (int r = 0; r < 16; ++r) rs += p[r];
    rs += __shfl_xor(rs, 32);
    l_run += rs;

    // ---- repack P (hi & lo splits) to PV A-fragments, 1-shuffle mix ----
    unsigned wh[8], wl[8];
#pragma unroll
    for (int i = 0; i < 8; ++i) {
      const float a = p[2 * i], c2 = p[2 * i + 1];
      const unsigned hword = cvt_pk_bf16(a, c2);
      const float ra = a - __uint_as_float(hword << 16);
      const float rc = c2 - __uint_as_float(hword & 0xffff0000u);
      wh[i] = hword;
      wl[i] = cvt_pk_bf16(ra, rc);
    }
    // lane<32 needs partner's lo into hi-slot; lane>=32 needs partner's hi
    // into lo-slot -> send the word the partner wants, one shuffle total.
    auto mix = [&](unsigned &lo_w, unsigned &hi_w) {
      const unsigned t = lhi ? lo_w : hi_w;
      const unsigned r = (unsigned)__shfl_xor((int)t, 32);
      lo_w = lhi ? r : lo_w;
      hi_w = lhi ? hi_w : r;
    };
    mix(wh[0], wh[2]); mix(wh[1], wh[3]); mix(wh[4], wh[6]); mix(wh[5], wh[7]);
    mix(wl[0], wl[2]); mix(wl[1], wl[3]); mix(wl[4], wl[6]); mix(wl[5], wl[7]);
    U4B8 pah0, pah1, pal0, pal1;
    pah0.u = make_uint4(wh[0], wh[1], wh[2], wh[3]);
    pah1.u = make_uint4(wh[4], wh[5], wh[6], wh[7]);
    pal0.u = make_uint4(wl[0], wl[1], wl[2], wl[3]);
    pal1.u = make_uint4(wl[4], wl[5], wl[6], wl[7]);

    // ---- PV half A (k 0..15), V from registers ----
    __builtin_amdgcn_s_setprio(1);
#pragma unroll
    for (int cf = 0; cf < 4; ++cf) {
      U4B8 vh, vl2;
      vh.u = vAh[cf]; vl2.u = vAl[cf];
      acc[cf] = __builtin_amdgcn_mfma_f32_32x32x16_bf16(pah0.v, vh.v,  acc[cf], 0, 0, 0);
      acc[cf] = __builtin_amdgcn_mfma_f32_32x32x16_bf16(pal0.v, vh.v,  acc[cf], 0, 0, 0);
      acc[cf] = __builtin_amdgcn_mfma_f32_32x32x16_bf16(pah0.v, vl2.v, acc[cf], 0, 0, 0);
    }
    __builtin_amdgcn_s_setprio(0);
    if (ch < 31) load_vA(ch + 1);     // prefetch (WAR keeps it after PV-A)

    // ---- PV half B (k 16..31) ----
    __builtin_amdgcn_s_setprio(1);
#pragma unroll
    for (int cf = 0; cf < 4; ++cf) {
      U4B8 vh, vl2;
      vh.u = vBh[cf]; vl2.u = vBl[cf];
      acc[cf] = __builtin_amdgcn_mfma_f32_32x32x16_bf16(pah1.v, vh.v,  acc[cf], 0, 0, 0);
      acc[cf] = __builtin_amdgcn_mfma_f32_32x32x16_bf16(pal1.v, vh.v,  acc[cf], 0, 0, 0);
      acc[cf] = __builtin_amdgcn_mfma_f32_32x32x16_bf16(pah1.v, vl2.v, acc[cf], 0, 0, 0);
    }
    __builtin_amdgcn_s_setprio(0);

    if (ch < 31) {
      load_vB(ch + 1);
      // Outstanding: K(ch+1)x2 (oldest) + vA8 + vB8 = 18 -> drain K only.
      SCHED0();
      asm volatile("s_waitcnt vmcnt(16)" ::: "memory");
      SBAR(); SCHED0();
    }
  }

  // ---- epilogue: normalize + store ----
  const float linv = 1.0f / l_run;
  float lr[16];
#pragma unroll
  for (int r = 0; r < 16; ++r)
    lr[r] = __shfl(linv, (r & 3) + 8 * (r >> 2) + 4 * lhi);
#pragma unroll
  for (int cf = 0; cf < 4; ++cf) {
    const int c = cw * 128 + cf * 32 + lrow;
    const int m = c >> 6, dd = c & 63;
#pragma unroll
    for (int r = 0; r < 16; ++r) {
      const int qr = (r & 3) + 8 * (r >> 2) + 4 * lhi;
      const int srow = qbase + qr;
      const size_t off = (((size_t)(b * S_ + srow)) * 8 + m) * 512 + h * 64 + dd;
      ao[off] = acc[cf][r] * lr[r];
    }
  }
}

// ---------------------------------------------------------------------------
// out_atoms = ao @ Wo^T + fused log-weight delta (unchanged).
// ---------------------------------------------------------------------------
__global__ __launch_bounds__(256) void k_out(
    const float* __restrict__ ao, const float* __restrict__ Wo,
    const float* __restrict__ Ww, const float* __restrict__ qlw,
    float* __restrict__ out)
{
  const int s2 = blockIdx.x;
  const int b = blockIdx.z;
  const int s0 = s2 * 2;
  const int tid = threadIdx.x, w = tid >> 6, lane = tid & 63;

  __shared__ __align__(16) float As[16 * 512];
  __shared__ __align__(16) float WoS[64 * 65];
  __shared__ float Os[16 * 64];

  const float* abase = ao + (size_t)((b * S_ + s0) * 8) * 512;
#pragma unroll
  for (int j = 0; j < 8; ++j) {
    const int i = tid + 256 * j;
    *(float4*)&As[4 * i] = *(const float4*)&abase[4 * i];
  }
  float acc[4] = {0.f, 0.f, 0.f, 0.f};
  for (int ft = 0; ft < 8; ++ft) {
    __syncthreads();
    for (int i = tid; i < 4096; i += 256) {
      const int dwo = i >> 6, fi = i & 63;
      WoS[fi * 65 + dwo] = Wo[dwo * 512 + ft * 64 + fi];
    }
    __syncthreads();
#pragma unroll 8
    for (int fi = 0; fi < 64; ++fi) {
      const float wv = WoS[fi * 65 + lane];
      const int f = ft * 64 + fi;
#pragma unroll
      for (int ri = 0; ri < 4; ++ri)
        acc[ri] = fmaf(As[(w * 4 + ri) * 512 + f], wv, acc[ri]);
    }
  }
#pragma unroll
  for (int ri = 0; ri < 4; ++ri) {
    const int row = w * 4 + ri;
    const int R = (b * S_ + s0) * 8 + row;
    out[(size_t)R * 64 + lane] = acc[ri];
    Os[row * 64 + lane] = acc[ri];
  }
  __syncthreads();
  if (w < 2) {
    float mean = 0.f;
#pragma unroll
    for (int m = 0; m < 8; ++m) mean += Os[(w * 8 + m) * 64 + lane];
    mean *= 0.125f;
    float dsel = 0.f;
#pragma unroll
    for (int mw = 0; mw < 8; ++mw) {
      float part = mean * Ww[mw * 64 + lane];
      part += __shfl_xor(part, 1);
      part += __shfl_xor(part, 2);
      part += __shfl_xor(part, 4);
      part += __shfl_xor(part, 8);
      part += __shfl_xor(part, 16);
      part += __shfl_xor(part, 32);
      if (lane == mw) dsel = part;
    }
    if (lane < 8) {
      const int idx = (b * S_ + s0 + w) * 8 + lane;
      out[1048576 + idx] = qlw[idx] + dsel;
    }
  }
}

// ---------------------------------------------------------------------------
extern "C" void kernel_launch(void* const* d_in, const int* in_sizes, int n_in,
                              void* d_out, int out_size, void* d_ws, size_t ws_size,
                              hipStream_t stream)
{
  const float* q_atoms = (const float*)d_in[0];
  const float* q_logw  = (const float*)d_in[1];
  const float* k_atoms = (const float*)d_in[2];
  const float* k_logw  = (const float*)d_in[3];
  const float* v_atoms = (const float*)d_in[4];
  const float* cosT  = (const float*)d_in[6];
  const float* sinT  = (const float*)d_in[7];
  const float* Wq    = (const float*)d_in[8];
  const float* Wk    = (const float*)d_in[9];
  const float* Wv    = (const float*)d_in[10];
  const float* Wo    = (const float*)d_in[11];
  const float* Ww    = (const float*)d_in[12];
  const float* logbw = (const float*)d_in[13];
  const float* rffb  = (const float*)d_in[14];
  float* out = (float*)d_out;

  char* wsb = (char*)d_ws;
  char* qrh = wsb;
  char* qrl = wsb + (4u << 20);
  char* krh = wsb + (8u << 20);
  char* krl = wsb + (12u << 20);
  char* vthi = wsb + (16u << 20);
  char* vtlo = wsb + (32u << 20);
  float* ao = (float*)(wsb + (48u << 20));

  const dim3 blk(256);
  k_proj_rff<<<dim3(128, 8, 2), blk, 0, stream>>>(q_atoms, q_logw, Wq, rffb, logbw, cosT, sinT, qrh, qrl, 0);
  k_proj_rff<<<dim3(128, 8, 2), blk, 0, stream>>>(k_atoms, k_logw, Wk, rffb, logbw, cosT, sinT, krh, krl, 1);
  k_proj_v  <<<dim3(128, 8, 2), blk, 0, stream>>>(v_atoms, Wv, vthi, vtlo);
  k_flash   <<<dim3(256), dim3(512), 0, stream>>>((const unsigned short*)qrh, (const unsigned short*)qrl,
                                                  krh, krl, vthi, vtlo, ao);
  k_out     <<<dim3(512, 1, 2), blk, 0, stream>>>(ao, Wo, Ww, q_logw, out);
}